// Round 18
// baseline (1330.614 us; speedup 1.0000x reference)
//
#include <hip/hip_runtime.h>
#include <hip/hip_bf16.h>
#include <stdint.h>

typedef __bf16 bf16x8 __attribute__((ext_vector_type(8)));
typedef __bf16 bf16x4 __attribute__((ext_vector_type(4)));
typedef float  f32x4  __attribute__((ext_vector_type(4)));

#define B_  16
#define KL  4096
#define D_  1024
#define NH  16
#define NROWS (B_*KL)   // 65536

__device__ __forceinline__ void gload_lds16(const void* g, void* l) {
  __builtin_amdgcn_global_load_lds(
      (__attribute__((address_space(1))) void*)g,
      (__attribute__((address_space(3))) void*)l, 16, 0, 0);
}

// ---------- small prep kernels ----------

__global__ __launch_bounds__(256) void conv_w_kernel(const float* __restrict__ wv,
                                                     const float* __restrict__ wo,
                                                     __bf16* __restrict__ dv,
                                                     __bf16* __restrict__ do_) {
  const bool second = blockIdx.x >= 1024;
  const int i = (second ? blockIdx.x - 1024 : blockIdx.x) * 256 + threadIdx.x;
  const float* s = second ? wo : wv;
  __bf16* d = second ? do_ : dv;
  float4 v = reinterpret_cast<const float4*>(s)[i];
  bf16x4 o;
  o[0] = (__bf16)v.x; o[1] = (__bf16)v.y; o[2] = (__bf16)v.z; o[3] = (__bf16)v.w;
  *reinterpret_cast<bf16x4*>(d + (size_t)i * 4) = o;
}

// Fused q-projection + wq_eff (verified R16 structure).
__global__ __launch_bounds__(256) void wqeff_kernel(const float* __restrict__ hs,
                                                    const float* __restrict__ Wq,
                                                    const float* __restrict__ bq,
                                                    const float* __restrict__ Wk,
                                                    const float* __restrict__ bk,
                                                    __bf16* __restrict__ whi,
                                                    __bf16* __restrict__ wlo,
                                                    float* __restrict__ cb) {
  const int h = blockIdx.x, b = blockIdx.y;
  const int tid = threadIdx.x;
  __shared__ float hsl[D_];
  __shared__ float ql[64];
  {
    float4 v = reinterpret_cast<const float4*>(hs + (size_t)b * D_)[tid];
    hsl[tid * 4] = v.x; hsl[tid * 4 + 1] = v.y;
    hsl[tid * 4 + 2] = v.z; hsl[tid * 4 + 3] = v.w;
  }
  __syncthreads();
  {
    const int d = tid >> 2, seg = tid & 3;
    const float* wr = Wq + (size_t)(h * 64 + d) * D_ + seg * 256;
    const float* xs = hsl + seg * 256;
    float p = 0.f;
    for (int i = 0; i < 256; i += 4) {
      float4 wv4 = *reinterpret_cast<const float4*>(wr + i);
      p += xs[i] * wv4.x + xs[i + 1] * wv4.y + xs[i + 2] * wv4.z + xs[i + 3] * wv4.w;
    }
    p += __shfl_xor(p, 1);
    p += __shfl_xor(p, 2);
    if (seg == 0) ql[d] = (p + bq[h * 64 + d]) * 0.125f;
  }
  __syncthreads();
  float a0 = 0, a1 = 0, a2 = 0, a3 = 0;
  for (int d = 0; d < 64; ++d) {
    float qv = ql[d];
    const float* wr = Wk + (size_t)(h * 64 + d) * D_;
    a0 += qv * wr[tid];
    a1 += qv * wr[tid + 256];
    a2 += qv * wr[tid + 512];
    a3 += qv * wr[tid + 768];
  }
  const size_t base = ((size_t)b * NH + h) * D_;
  float a[4] = {a0, a1, a2, a3};
#pragma unroll
  for (int j = 0; j < 4; ++j) {
    __bf16 hi = (__bf16)a[j];
    whi[base + j * 256 + tid] = hi;
    wlo[base + j * 256 + tid] = (__bf16)(a[j] - (float)hi);
  }
  if (tid < 64) {
    float p = ql[tid] * bk[h * 64 + tid];
    p += __shfl_down(p, 32); p += __shfl_down(p, 16); p += __shfl_down(p, 8);
    p += __shfl_down(p, 4);  p += __shfl_down(p, 2);  p += __shfl_down(p, 1);
    if (tid == 0) cb[b * NH + h] = p;
  }
}

// Scores via split-bf16 MFMA, K-SPLIT x2 (verified R16 structure).
__global__ __launch_bounds__(512) void scores_mfma_kernel(
    const float* __restrict__ kvs,   // [B, KL, D]
    const __bf16* __restrict__ whi,  // [B*NH, D]
    const __bf16* __restrict__ wlo,  // [B*NH, D]
    const float* __restrict__ cb,    // [B*NH]
    float* __restrict__ attn,        // [B*KL, NH]
    __bf16* __restrict__ kvd) {      // [B*KL, D]
  __shared__ f32x4 part[4][64];
  const int b = blockIdx.y;
  const int tid = threadIdx.x;
  const int lane = tid & 63, wv = tid >> 6;       // 8 waves
  const int rg = wv & 3;                          // row-group 0..3
  const int kh = wv >> 2;                         // K-half 0/1
  const int r16 = lane & 15, kgrp = lane >> 4;
  const int row0 = blockIdx.x * 64 + rg * 16;
  const size_t grow = (size_t)b * KL + row0;
  const int kbase = kh * 512;

  const float* xrow = kvs + (grow + r16) * D_ + kbase + kgrp * 8;
  __bf16*      krow = kvd + (grow + r16) * D_ + kbase + kgrp * 8;
  const __bf16* wh = whi + ((size_t)b * NH + r16) * D_ + kbase + kgrp * 8;
  const __bf16* wl = wlo + ((size_t)b * NH + r16) * D_ + kbase + kgrp * 8;

  f32x4 acc0 = {}, acc1 = {};

#define SPROC(xx0, xx1, kk)                                                     \
  {                                                                             \
    bf16x8 bh = *reinterpret_cast<const bf16x8*>(wh + (kk));                    \
    bf16x8 bl = *reinterpret_cast<const bf16x8*>(wl + (kk));                    \
    float xs[8] = {xx0.x, xx0.y, xx0.z, xx0.w, xx1.x, xx1.y, xx1.z, xx1.w};     \
    bf16x8 hi, lo;                                                              \
    _Pragma("unroll") for (int i = 0; i < 8; ++i) {                             \
      __bf16 h = (__bf16)xs[i];                                                 \
      hi[i] = h;                                                                \
      lo[i] = (__bf16)(xs[i] - (float)h);                                       \
    }                                                                           \
    *reinterpret_cast<bf16x8*>(krow + (kk)) = hi;                               \
    acc0 = __builtin_amdgcn_mfma_f32_16x16x32_bf16(hi, bh, acc0, 0, 0, 0);      \
    acc1 = __builtin_amdgcn_mfma_f32_16x16x32_bf16(hi, bl, acc1, 0, 0, 0);      \
    acc1 = __builtin_amdgcn_mfma_f32_16x16x32_bf16(lo, bh, acc1, 0, 0, 0);      \
  }

  float4 xa0 = *reinterpret_cast<const float4*>(xrow);
  float4 xa1 = *reinterpret_cast<const float4*>(xrow + 4);
  float4 xb0 = *reinterpret_cast<const float4*>(xrow + 32);
  float4 xb1 = *reinterpret_cast<const float4*>(xrow + 36);
  for (int k0 = 0; k0 < 512; k0 += 64) {
    float4 na0, na1, nb0, nb1;
    if (k0 + 64 < 512) {
      na0 = *reinterpret_cast<const float4*>(xrow + k0 + 64);
      na1 = *reinterpret_cast<const float4*>(xrow + k0 + 68);
      nb0 = *reinterpret_cast<const float4*>(xrow + k0 + 96);
      nb1 = *reinterpret_cast<const float4*>(xrow + k0 + 100);
    }
    SPROC(xa0, xa1, k0);
    SPROC(xb0, xb1, k0 + 32);
    xa0 = na0; xa1 = na1; xb0 = nb0; xb1 = nb1;
  }
#undef SPROC

  if (kh == 1) {
    f32x4 s = acc0;
#pragma unroll
    for (int r = 0; r < 4; ++r) s[r] += acc1[r];
    part[rg][lane] = s;
  }
  __syncthreads();
  if (kh == 0) {
    f32x4 p = part[rg][lane];
    const float c = cb[b * NH + r16];             // head = r16 in C layout
#pragma unroll
    for (int r = 0; r < 4; ++r) {
      const int orow = row0 + kgrp * 4 + r;
      float s = acc0[r] + acc1[r] + p[r] + c;
      attn[((size_t)b * KL + orow) * NH + r16] = fminf(fmaxf(s, 0.f), 1.f);
    }
  }
}

// ---------- 256x256 / BK=32 bf16 GEMM, 64KB LDS -> 2 blocks/CU (TLP) ----------
// A/B experiment for GEMM1. 512 thr = 8 waves (2M x 4N), wave tile 128x64.
// 32 K-tiles, 2 phases each: {ds_read; [p1: stage BOTH next tiles]; barrier;
// lgkmcnt(0); sched_barrier; setprio; 16 MFMA; setprio; [p2: vmcnt(0)]; barrier}
// The per-tile vmcnt(0) drain (age 2 phases) is hidden by the co-resident
// second block (TLP), which the 128KB/BK=64 kernel cannot have.
// Swizzle (32-col rows): LDS[R][slot s] holds global seg s ^ ((R>>1)&3);
// read slot = kgrp ^ ((r16>>1)&3)  (residual 2-way conflict = free, m136).
template <bool GATE>
__global__ __launch_bounds__(512, 4) void gemm_bk32(const __bf16* __restrict__ A,
                                                    const __bf16* __restrict__ Bt,
                                                    const float* __restrict__ bias,
                                                    const float* __restrict__ gate,
                                                    void* __restrict__ Cp) {
  __shared__ __bf16 As[2][256 * 32];
  __shared__ __bf16 Bs[2][256 * 32];
  const int tid = threadIdx.x;
  const int lane = tid & 63, wid = tid >> 6;
  const int wm = wid >> 2, wn = wid & 3;           // 2 x 4 waves
  const int r16 = lane & 15, kgrp = lane >> 4;
  const int bswz = (blockIdx.x & 7) * 128 + (blockIdx.x >> 3);
  const int m0 = (bswz >> 2) * 256;
  const int n0 = (bswz & 3) * 256;

  // staging: chunk c = 16 rows x 32 cols (1KB); c = wid*2 + j (16 chunks/tile).
  const int srow = lane >> 2;                              // row within chunk
  const int scol = (((lane & 3) ^ ((lane >> 3) & 3))) * 8; // pre-swizzled seg

  const int sw = (kgrp ^ ((r16 >> 1) & 3)) * 8;            // ds_read slot (elems)

  f32x4 acc[8][4] = {};   // [mh*4+f][nh*2+g]

#define STAGE_T32(dstbuf, srcp, base0, k0)                                      \
  {                                                                             \
    _Pragma("unroll") for (int j = 0; j < 2; ++j) {                             \
      const int c = wid * 2 + j;                                                \
      gload_lds16((srcp) + (size_t)((base0) + c * 16 + srow) * D_ + (k0) + scol,\
                  &(dstbuf)[c * 512]);                                          \
    }                                                                           \
  }

#define LOAD_BV32(Bb)                                                           \
  _Pragma("unroll") for (int nh = 0; nh < 2; ++nh)                              \
    _Pragma("unroll") for (int g = 0; g < 2; ++g)                               \
      bv[nh * 2 + g] = *reinterpret_cast<const bf16x8*>(                        \
          &(Bb)[(nh * 128 + wn * 32 + g * 16 + r16) * 32 + sw]);

#define LOAD_AV32(Ab, mh)                                                       \
  _Pragma("unroll") for (int f = 0; f < 4; ++f)                                 \
    av[f] = *reinterpret_cast<const bf16x8*>(                                   \
        &(Ab)[((mh) * 128 + wm * 64 + f * 16 + r16) * 32 + sw]);

#define MFMA_P32(mh)                                                            \
  {                                                                             \
    __builtin_amdgcn_s_setprio(1);                                              \
    _Pragma("unroll") for (int f = 0; f < 4; ++f)                               \
      _Pragma("unroll") for (int q = 0; q < 4; ++q)                             \
        acc[(mh) * 4 + f][q] = __builtin_amdgcn_mfma_f32_16x16x32_bf16(         \
            av[f], bv[q], acc[(mh) * 4 + f][q], 0, 0, 0);                       \
    __builtin_amdgcn_s_setprio(0);                                              \
  }

#define WAITLGKM32()                                                            \
  asm volatile("s_waitcnt lgkmcnt(0)" ::: "memory");                            \
  __builtin_amdgcn_sched_barrier(0);

  // prologue: tile 0 (A+B, 4 loads/thread), full drain (prologue only).
  STAGE_T32(As[0], A,  m0, 0);
  STAGE_T32(Bs[0], Bt, n0, 0);
  asm volatile("s_waitcnt vmcnt(0)" ::: "memory");
  __builtin_amdgcn_s_barrier();

  const int NT = D_ / 32;   // 32
  for (int t = 0; t < NT; ++t) {
    __bf16* Ab = (t & 1) ? As[1] : As[0];
    __bf16* Bb = (t & 1) ? Bs[1] : Bs[0];
    __bf16* An = (t & 1) ? As[0] : As[1];
    __bf16* Bn = (t & 1) ? Bs[0] : Bs[1];
    const int k1 = (t + 1) * 32;
    const bool pf = (t < NT - 1);
    bf16x8 bv[4], av[4];

    // ---- p1: ds_read B(t)+A(t)mh0; stage A(t+1)+B(t+1) ----
    LOAD_BV32(Bb);
    LOAD_AV32(Ab, 0);
    if (pf) {
      STAGE_T32(An, A,  m0, k1);
      STAGE_T32(Bn, Bt, n0, k1);
    }
    __builtin_amdgcn_s_barrier();
    WAITLGKM32();
    MFMA_P32(0);
    __builtin_amdgcn_s_barrier();
    // ---- p2: ds_read A(t)mh1; retire next tile at end ----
    LOAD_AV32(Ab, 1);
    __builtin_amdgcn_s_barrier();
    WAITLGKM32();
    MFMA_P32(1);
    if (pf) asm volatile("s_waitcnt vmcnt(0)" ::: "memory");
    __builtin_amdgcn_s_barrier();
  }

  // epilogue. C/D layout: col = lane&15, row = (lane>>4)*4 + reg
#pragma unroll
  for (int mh = 0; mh < 2; ++mh) {
#pragma unroll
    for (int f = 0; f < 4; ++f) {
      const int row0 = m0 + mh * 128 + wm * 64 + f * 16 + kgrp * 4;
#pragma unroll
      for (int nh = 0; nh < 2; ++nh) {
#pragma unroll
        for (int g = 0; g < 2; ++g) {
          const int col = n0 + nh * 128 + wn * 32 + g * 16 + r16;
          const float bc = bias[col];
          const int head = col >> 6;
          f32x4 v = acc[mh * 4 + f][nh * 2 + g];
#pragma unroll
          for (int r = 0; r < 4; ++r) {
            const int row = row0 + r;
            if constexpr (GATE) {
              float gg = gate[(size_t)row * NH + head];
              ((__bf16*)Cp)[(size_t)row * D_ + col] = (__bf16)((v[r] + bc) * gg);
            } else {
              ((float*)Cp)[(size_t)row * D_ + col] = v[r] + bc;
            }
          }
        }
      }
    }
  }
#undef STAGE_T32
#undef LOAD_BV32
#undef LOAD_AV32
#undef MFMA_P32
#undef WAITLGKM32
}

// ---------- 256x256 / BK=64 bf16 MFMA GEMM, 8-barrier m201-style phases ----------
// EXACT R12/R15/R16 structure (best measured: 168-172 µs; three ledger
// variants all regressed -- frozen).
template <bool GATE>
__global__ __launch_bounds__(512, 2) void gemm_nt(const __bf16* __restrict__ A,
                                                  const __bf16* __restrict__ Bt,
                                                  const float* __restrict__ bias,
                                                  const float* __restrict__ gate,
                                                  void* __restrict__ Cp) {
  __shared__ __bf16 As[2][256 * 64];
  __shared__ __bf16 Bs[2][256 * 64];
  const int tid = threadIdx.x;
  const int lane = tid & 63, wid = tid >> 6;
  const int wm = wid >> 2, wn = wid & 3;           // 2 x 4 waves
  const int r16 = lane & 15, kgrp = lane >> 4;
  const int bswz = (blockIdx.x & 7) * 128 + (blockIdx.x >> 3);
  const int m0 = (bswz >> 2) * 256;
  const int n0 = (bswz & 3) * 256;

  const int srow = lane >> 3;
  const int scol = ((lane & 7) ^ srow) * 8;        // pre-swizzled source col

  const int sw0 = ((kgrp) ^ (r16 & 7)) * 8;
  const int sw1 = ((4 + kgrp) ^ (r16 & 7)) * 8;

  f32x4 acc[8][4] = {};   // [mh*4+f][nh*2+g]

#define STAGE_HALF(dstbuf, srcp, base0, h, k0)                                  \
  {                                                                             \
    _Pragma("unroll") for (int j = 0; j < 2; ++j) {                             \
      const int c = (h) * 16 + wid * 2 + j;                                     \
      gload_lds16((srcp) + (size_t)((base0) + c * 8 + srow) * D_ + (k0) + scol, \
                  &(dstbuf)[c * 512]);                                          \
    }                                                                           \
  }

#define LOAD_BV(Bb, sw)                                                         \
  _Pragma("unroll") for (int nh = 0; nh < 2; ++nh)                              \
    _Pragma("unroll") for (int g = 0; g < 2; ++g)                               \
      bv[nh * 2 + g] = *reinterpret_cast<const bf16x8*>(                        \
          &(Bb)[(nh * 128 + wn * 32 + g * 16 + r16) * 64 + (sw)]);

#define LOAD_AV(Ab, mh, sw)                                                     \
  _Pragma("unroll") for (int f = 0; f < 4; ++f)                                 \
    av[f] = *reinterpret_cast<const bf16x8*>(                                   \
        &(Ab)[((mh) * 128 + wm * 64 + f * 16 + r16) * 64 + (sw)]);

#define MFMA_PHASE(mh)                                                          \
  {                                                                             \
    __builtin_amdgcn_s_setprio(1);                                              \
    _Pragma("unroll") for (int f = 0; f < 4; ++f)                               \
      _Pragma("unroll") for (int q = 0; q < 4; ++q)                             \
        acc[(mh) * 4 + f][q] = __builtin_amdgcn_mfma_f32_16x16x32_bf16(         \
            av[f], bv[q], acc[(mh) * 4 + f][q], 0, 0, 0);                       \
    __builtin_amdgcn_s_setprio(0);                                              \
  }

#define WAITLGKM()                                                              \
  asm volatile("s_waitcnt lgkmcnt(0)" ::: "memory");                            \
  __builtin_amdgcn_sched_barrier(0);

  // prologue: tile 0 = Bh0,Bh1,Ah0,Ah1; retire all but Ah1(0).
  STAGE_HALF(Bs[0], Bt, n0, 0, 0);
  STAGE_HALF(Bs[0], Bt, n0, 1, 0);
  STAGE_HALF(As[0], A,  m0, 0, 0);
  STAGE_HALF(As[0], A,  m0, 1, 0);
  asm volatile("s_waitcnt vmcnt(2)" ::: "memory");
  __builtin_amdgcn_s_barrier();

  const int NT = D_ / 64;   // 16
  for (int t = 0; t < NT; ++t) {
    __bf16* Ab = (t & 1) ? As[1] : As[0];
    __bf16* Bb = (t & 1) ? Bs[1] : Bs[0];
    __bf16* An = (t & 1) ? As[0] : As[1];
    __bf16* Bn = (t & 1) ? Bs[0] : Bs[1];
    const int k1 = (t + 1) * 64;
    const bool pf = (t < NT - 1);
    bf16x8 bv[4], av[4];

    // ---- p1: (mh0, kk0); stage Bh0(t+1); retire Ah1(t) ----
    LOAD_BV(Bb, sw0);
    LOAD_AV(Ab, 0, sw0);
    if (pf) STAGE_HALF(Bn, Bt, n0, 0, k1);
    __builtin_amdgcn_s_barrier();
    WAITLGKM();
    MFMA_PHASE(0);
    if (pf) asm volatile("s_waitcnt vmcnt(2)" ::: "memory");
    else    asm volatile("s_waitcnt vmcnt(0)" ::: "memory");
    __builtin_amdgcn_s_barrier();
    // ---- p2: (mh1, kk0); stage Bh1(t+1) ----
    LOAD_AV(Ab, 1, sw0);
    if (pf) STAGE_HALF(Bn, Bt, n0, 1, k1);
    __builtin_amdgcn_s_barrier();
    WAITLGKM();
    MFMA_PHASE(1);
    __builtin_amdgcn_s_barrier();
    // ---- p3: (mh0, kk1); stage Ah0(t+1) ----
    LOAD_BV(Bb, sw1);
    LOAD_AV(Ab, 0, sw1);
    if (pf) STAGE_HALF(An, A, m0, 0, k1);
    __builtin_amdgcn_s_barrier();
    WAITLGKM();
    MFMA_PHASE(0);
    __builtin_amdgcn_s_barrier();
    // ---- p4: (mh1, kk1); stage Ah1(t+1); retire B(t+1)+Ah0(t+1) ----
    LOAD_AV(Ab, 1, sw1);
    if (pf) STAGE_HALF(An, A, m0, 1, k1);
    __builtin_amdgcn_s_barrier();
    WAITLGKM();
    MFMA_PHASE(1);
    if (pf) asm volatile("s_waitcnt vmcnt(2)" ::: "memory");
    __builtin_amdgcn_s_barrier();
  }

  // epilogue. C/D layout: col = lane&15, row = (lane>>4)*4 + reg
#pragma unroll
  for (int mh = 0; mh < 2; ++mh) {
#pragma unroll
    for (int f = 0; f < 4; ++f) {
      const int row0 = m0 + mh * 128 + wm * 64 + f * 16 + kgrp * 4;
#pragma unroll
      for (int nh = 0; nh < 2; ++nh) {
#pragma unroll
        for (int g = 0; g < 2; ++g) {
          const int col = n0 + nh * 128 + wn * 32 + g * 16 + r16;
          const float bc = bias[col];
          const int head = col >> 6;
          f32x4 v = acc[mh * 4 + f][nh * 2 + g];
#pragma unroll
          for (int r = 0; r < 4; ++r) {
            const int row = row0 + r;
            if constexpr (GATE) {
              float gg = gate[(size_t)row * NH + head];
              ((__bf16*)Cp)[(size_t)row * D_ + col] = (__bf16)((v[r] + bc) * gg);
            } else {
              ((float*)Cp)[(size_t)row * D_ + col] = v[r] + bc;
            }
          }
        }
      }
    }
  }
#undef STAGE_HALF
#undef LOAD_BV
#undef LOAD_AV
#undef MFMA_PHASE
#undef WAITLGKM
}

extern "C" void kernel_launch(void* const* d_in, const int* in_sizes, int n_in,
                              void* d_out, int out_size, void* d_ws, size_t ws_size,
                              hipStream_t stream) {
  const float* hs  = (const float*)d_in[0];   // [16,1,1024]
  const float* kvs = (const float*)d_in[1];   // [16,4096,1024]
  const float* Wq  = (const float*)d_in[2];
  const float* bq  = (const float*)d_in[3];
  const float* Wk  = (const float*)d_in[4];
  const float* bk  = (const float*)d_in[5];
  const float* Wv  = (const float*)d_in[6];
  const float* bv  = (const float*)d_in[7];
  const float* Wo  = (const float*)d_in[8];
  const float* bo  = (const float*)d_in[9];
  float* out = (float*)d_out;

  char* w = (char*)d_ws;
  __bf16* ctx  = (__bf16*)w;  w += (size_t)NROWS * D_ * 2;    // 128 MB gated context (bf16)
  float*  attn = (float*)w;   w += (size_t)NROWS * NH * 4;    // 4 MB gate [row][head]
  __bf16* WvB  = (__bf16*)w;  w += (size_t)D_ * D_ * 2;       // 2 MB
  __bf16* WoB  = (__bf16*)w;  w += (size_t)D_ * D_ * 2;       // 2 MB
  __bf16* whi  = (__bf16*)w;  w += (size_t)B_ * NH * D_ * 2;  // 512 KB
  __bf16* wlo  = (__bf16*)w;  w += (size_t)B_ * NH * D_ * 2;  // 512 KB
  float*  cbuf = (float*)w;   w += B_ * NH * 4;               // 1 KB

  // bf16 copy of kvs lives in d_out (128 MB of its 256 MB); written by
  // scores_mfma (== bf16(kvs) exactly), consumed by GEMM1, then fully
  // overwritten by GEMM2's epilogue. No cross-call state.
  __bf16* kvsB = (__bf16*)d_out;

  conv_w_kernel<<<2048, 256, 0, stream>>>(Wv, Wo, WvB, WoB);
  wqeff_kernel<<<dim3(NH, B_), 256, 0, stream>>>(hs, Wq, bq, Wk, bk, whi, wlo, cbuf);
  scores_mfma_kernel<<<dim3(KL / 64, B_), 512, 0, stream>>>(kvs, whi, wlo, cbuf, attn, kvsB);
  gemm_bk32<true ><<<1024, 512, 0, stream>>>(kvsB, WvB, bv, attn, ctx);   // A/B: TLP variant
  gemm_nt  <false><<<1024, 512, 0, stream>>>(ctx, WoB, bo, (const float*)nullptr, (void*)out);
}

// Round 19
// 474.903 us; speedup vs baseline: 2.8019x; 2.8019x over previous
//
#include <hip/hip_runtime.h>
#include <hip/hip_bf16.h>
#include <stdint.h>

typedef __bf16 bf16x8 __attribute__((ext_vector_type(8)));
typedef __bf16 bf16x4 __attribute__((ext_vector_type(4)));
typedef float  f32x4  __attribute__((ext_vector_type(4)));

#define B_  16
#define KL  4096
#define D_  1024
#define NH  16
#define NROWS (B_*KL)   // 65536

__device__ __forceinline__ void gload_lds16(const void* g, void* l) {
  __builtin_amdgcn_global_load_lds(
      (__attribute__((address_space(1))) void*)g,
      (__attribute__((address_space(3))) void*)l, 16, 0, 0);
}

// ---------- small prep kernels ----------

__global__ __launch_bounds__(256) void conv_w_kernel(const float* __restrict__ wv,
                                                     const float* __restrict__ wo,
                                                     __bf16* __restrict__ dv,
                                                     __bf16* __restrict__ do_) {
  const bool second = blockIdx.x >= 1024;
  const int i = (second ? blockIdx.x - 1024 : blockIdx.x) * 256 + threadIdx.x;
  const float* s = second ? wo : wv;
  __bf16* d = second ? do_ : dv;
  float4 v = reinterpret_cast<const float4*>(s)[i];
  bf16x4 o;
  o[0] = (__bf16)v.x; o[1] = (__bf16)v.y; o[2] = (__bf16)v.z; o[3] = (__bf16)v.w;
  *reinterpret_cast<bf16x4*>(d + (size_t)i * 4) = o;
}

// Fused q-projection + wq_eff (verified R16 structure).
__global__ __launch_bounds__(256) void wqeff_kernel(const float* __restrict__ hs,
                                                    const float* __restrict__ Wq,
                                                    const float* __restrict__ bq,
                                                    const float* __restrict__ Wk,
                                                    const float* __restrict__ bk,
                                                    __bf16* __restrict__ whi,
                                                    __bf16* __restrict__ wlo,
                                                    float* __restrict__ cb) {
  const int h = blockIdx.x, b = blockIdx.y;
  const int tid = threadIdx.x;
  __shared__ float hsl[D_];
  __shared__ float ql[64];
  {
    float4 v = reinterpret_cast<const float4*>(hs + (size_t)b * D_)[tid];
    hsl[tid * 4] = v.x; hsl[tid * 4 + 1] = v.y;
    hsl[tid * 4 + 2] = v.z; hsl[tid * 4 + 3] = v.w;
  }
  __syncthreads();
  {
    const int d = tid >> 2, seg = tid & 3;
    const float* wr = Wq + (size_t)(h * 64 + d) * D_ + seg * 256;
    const float* xs = hsl + seg * 256;
    float p = 0.f;
    for (int i = 0; i < 256; i += 4) {
      float4 wv4 = *reinterpret_cast<const float4*>(wr + i);
      p += xs[i] * wv4.x + xs[i + 1] * wv4.y + xs[i + 2] * wv4.z + xs[i + 3] * wv4.w;
    }
    p += __shfl_xor(p, 1);
    p += __shfl_xor(p, 2);
    if (seg == 0) ql[d] = (p + bq[h * 64 + d]) * 0.125f;
  }
  __syncthreads();
  float a0 = 0, a1 = 0, a2 = 0, a3 = 0;
  for (int d = 0; d < 64; ++d) {
    float qv = ql[d];
    const float* wr = Wk + (size_t)(h * 64 + d) * D_;
    a0 += qv * wr[tid];
    a1 += qv * wr[tid + 256];
    a2 += qv * wr[tid + 512];
    a3 += qv * wr[tid + 768];
  }
  const size_t base = ((size_t)b * NH + h) * D_;
  float a[4] = {a0, a1, a2, a3};
#pragma unroll
  for (int j = 0; j < 4; ++j) {
    __bf16 hi = (__bf16)a[j];
    whi[base + j * 256 + tid] = hi;
    wlo[base + j * 256 + tid] = (__bf16)(a[j] - (float)hi);
  }
  if (tid < 64) {
    float p = ql[tid] * bk[h * 64 + tid];
    p += __shfl_down(p, 32); p += __shfl_down(p, 16); p += __shfl_down(p, 8);
    p += __shfl_down(p, 4);  p += __shfl_down(p, 2);  p += __shfl_down(p, 1);
    if (tid == 0) cb[b * NH + h] = p;
  }
}

// Scores via split-bf16 MFMA, K-SPLIT x2 (verified R16 structure).
__global__ __launch_bounds__(512) void scores_mfma_kernel(
    const float* __restrict__ kvs,   // [B, KL, D]
    const __bf16* __restrict__ whi,  // [B*NH, D]
    const __bf16* __restrict__ wlo,  // [B*NH, D]
    const float* __restrict__ cb,    // [B*NH]
    float* __restrict__ attn,        // [B*KL, NH]
    __bf16* __restrict__ kvd) {      // [B*KL, D]
  __shared__ f32x4 part[4][64];
  const int b = blockIdx.y;
  const int tid = threadIdx.x;
  const int lane = tid & 63, wv = tid >> 6;       // 8 waves
  const int rg = wv & 3;                          // row-group 0..3
  const int kh = wv >> 2;                         // K-half 0/1
  const int r16 = lane & 15, kgrp = lane >> 4;
  const int row0 = blockIdx.x * 64 + rg * 16;
  const size_t grow = (size_t)b * KL + row0;
  const int kbase = kh * 512;

  const float* xrow = kvs + (grow + r16) * D_ + kbase + kgrp * 8;
  __bf16*      krow = kvd + (grow + r16) * D_ + kbase + kgrp * 8;
  const __bf16* wh = whi + ((size_t)b * NH + r16) * D_ + kbase + kgrp * 8;
  const __bf16* wl = wlo + ((size_t)b * NH + r16) * D_ + kbase + kgrp * 8;

  f32x4 acc0 = {}, acc1 = {};

#define SPROC(xx0, xx1, kk)                                                     \
  {                                                                             \
    bf16x8 bh = *reinterpret_cast<const bf16x8*>(wh + (kk));                    \
    bf16x8 bl = *reinterpret_cast<const bf16x8*>(wl + (kk));                    \
    float xs[8] = {xx0.x, xx0.y, xx0.z, xx0.w, xx1.x, xx1.y, xx1.z, xx1.w};     \
    bf16x8 hi, lo;                                                              \
    _Pragma("unroll") for (int i = 0; i < 8; ++i) {                             \
      __bf16 h = (__bf16)xs[i];                                                 \
      hi[i] = h;                                                                \
      lo[i] = (__bf16)(xs[i] - (float)h);                                       \
    }                                                                           \
    *reinterpret_cast<bf16x8*>(krow + (kk)) = hi;                               \
    acc0 = __builtin_amdgcn_mfma_f32_16x16x32_bf16(hi, bh, acc0, 0, 0, 0);      \
    acc1 = __builtin_amdgcn_mfma_f32_16x16x32_bf16(hi, bl, acc1, 0, 0, 0);      \
    acc1 = __builtin_amdgcn_mfma_f32_16x16x32_bf16(lo, bh, acc1, 0, 0, 0);      \
  }

  float4 xa0 = *reinterpret_cast<const float4*>(xrow);
  float4 xa1 = *reinterpret_cast<const float4*>(xrow + 4);
  float4 xb0 = *reinterpret_cast<const float4*>(xrow + 32);
  float4 xb1 = *reinterpret_cast<const float4*>(xrow + 36);
  for (int k0 = 0; k0 < 512; k0 += 64) {
    float4 na0, na1, nb0, nb1;
    if (k0 + 64 < 512) {
      na0 = *reinterpret_cast<const float4*>(xrow + k0 + 64);
      na1 = *reinterpret_cast<const float4*>(xrow + k0 + 68);
      nb0 = *reinterpret_cast<const float4*>(xrow + k0 + 96);
      nb1 = *reinterpret_cast<const float4*>(xrow + k0 + 100);
    }
    SPROC(xa0, xa1, k0);
    SPROC(xb0, xb1, k0 + 32);
    xa0 = na0; xa1 = na1; xb0 = nb0; xb1 = nb1;
  }
#undef SPROC

  if (kh == 1) {
    f32x4 s = acc0;
#pragma unroll
    for (int r = 0; r < 4; ++r) s[r] += acc1[r];
    part[rg][lane] = s;
  }
  __syncthreads();
  if (kh == 0) {
    f32x4 p = part[rg][lane];
    const float c = cb[b * NH + r16];             // head = r16 in C layout
#pragma unroll
    for (int r = 0; r < 4; ++r) {
      const int orow = row0 + kgrp * 4 + r;
      float s = acc0[r] + acc1[r] + p[r] + c;
      attn[((size_t)b * KL + orow) * NH + r16] = fminf(fmaxf(s, 0.f), 1.f);
    }
  }
}

// ---------- 128x128 / BK=64 GEMM, R12 phase pattern, 64KB LDS -> 2 blocks/CU ----
// 256 thr = 4 waves (2M x 2N); wave tile 64x64 (rows wm*64+mh*32+f*16,
// cols wn*64+g*16). Phase = (mh,kk), 8 MFMA each, same 8-barrier pattern and
// IDENTICAL per-thread ledger as the frozen R12 kernel (2 loads/STAGE):
//   prologue vmcnt(2); p1 stage Bh0'+vmcnt(2); p2 Bh1'; p3 Ah0'; p4 Ah1'+vmcnt(2).
// A-half h = rows {h*32..h*32+31} u {64+h*32..64+h*32+31} so phase-mh reads
// exactly half-mh for BOTH wm. Staging rows are 128B (full line; bk32 lesson).
// XCD swizzle: 8 consecutive n-tiles of one m-row per XCD -> A panel (256KB)
// L2-resident. Swizzle involution identical to R12 (rows are 64 cols).
template <bool GATE>
__global__ __launch_bounds__(256, 2) void gemm_128(const __bf16* __restrict__ A,
                                                   const __bf16* __restrict__ Bt,
                                                   const float* __restrict__ bias,
                                                   const float* __restrict__ gate,
                                                   void* __restrict__ Cp) {
  __shared__ __bf16 As[2][128 * 64];
  __shared__ __bf16 Bs[2][128 * 64];
  const int tid = threadIdx.x;
  const int lane = tid & 63, wid = tid >> 6;       // 4 waves
  const int wm = wid >> 1, wn = wid & 1;           // 2 x 2
  const int r16 = lane & 15, kgrp = lane >> 4;
  // 4096 blocks, 8 XCDs x 512; m-tiles 512, n-tiles 8
  const int bswz = (blockIdx.x & 7) * 512 + (blockIdx.x >> 3);
  const int m0 = (bswz >> 3) * 128;
  const int n0 = (bswz & 7) * 128;

  const int srow = lane >> 3;                      // 0..7
  const int scol = ((lane & 7) ^ srow) * 8;        // pre-swizzled source col

  const int sw0 = ((kgrp) ^ (r16 & 7)) * 8;
  const int sw1 = ((4 + kgrp) ^ (r16 & 7)) * 8;

  f32x4 acc[4][4] = {};   // [mh*2+f][g]

// chunk c = 8 rows x 64 cols (1KB). B half h: chunks h*8 + wid*2 + j.
#define STAGE_B128(dstbuf, h, k0)                                               \
  {                                                                             \
    _Pragma("unroll") for (int j = 0; j < 2; ++j) {                             \
      const int c = (h) * 8 + wid * 2 + j;                                      \
      gload_lds16(Bt + (size_t)(n0 + c * 8 + srow) * D_ + (k0) + scol,          \
                  &(dstbuf)[c * 512]);                                          \
    }                                                                           \
  }
// A half h: chunks {h*4 + wid} and {8 + h*4 + wid} (rows h*32.. and 64+h*32..)
#define STAGE_A128(dstbuf, h, k0)                                               \
  {                                                                             \
    {                                                                           \
      const int c = (h) * 4 + wid;                                              \
      gload_lds16(A + (size_t)(m0 + c * 8 + srow) * D_ + (k0) + scol,           \
                  &(dstbuf)[c * 512]);                                          \
    }                                                                           \
    {                                                                           \
      const int c = 8 + (h) * 4 + wid;                                          \
      gload_lds16(A + (size_t)(m0 + c * 8 + srow) * D_ + (k0) + scol,           \
                  &(dstbuf)[c * 512]);                                          \
    }                                                                           \
  }

#define LOAD_BV128(Bb, sw)                                                      \
  _Pragma("unroll") for (int g = 0; g < 4; ++g)                                 \
    bv[g] = *reinterpret_cast<const bf16x8*>(                                   \
        &(Bb)[(wn * 64 + g * 16 + r16) * 64 + (sw)]);

#define LOAD_AV128(Ab, mh, sw)                                                  \
  _Pragma("unroll") for (int f = 0; f < 2; ++f)                                 \
    av[f] = *reinterpret_cast<const bf16x8*>(                                   \
        &(Ab)[(wm * 64 + (mh) * 32 + f * 16 + r16) * 64 + (sw)]);

#define MFMA_P128(mh)                                                           \
  {                                                                             \
    __builtin_amdgcn_s_setprio(1);                                              \
    _Pragma("unroll") for (int f = 0; f < 2; ++f)                               \
      _Pragma("unroll") for (int g = 0; g < 4; ++g)                             \
        acc[(mh) * 2 + f][g] = __builtin_amdgcn_mfma_f32_16x16x32_bf16(         \
            av[f], bv[g], acc[(mh) * 2 + f][g], 0, 0, 0);                       \
    __builtin_amdgcn_s_setprio(0);                                              \
  }

#define WAITLGKM128()                                                           \
  asm volatile("s_waitcnt lgkmcnt(0)" ::: "memory");                            \
  __builtin_amdgcn_sched_barrier(0);

  // prologue: Bh0,Bh1,Ah0,Ah1 (8 loads/thread); retire all but Ah1(0).
  STAGE_B128(Bs[0], 0, 0);
  STAGE_B128(Bs[0], 1, 0);
  STAGE_A128(As[0], 0, 0);
  STAGE_A128(As[0], 1, 0);
  asm volatile("s_waitcnt vmcnt(2)" ::: "memory");
  __builtin_amdgcn_s_barrier();

  const int NT = D_ / 64;   // 16
  for (int t = 0; t < NT; ++t) {
    __bf16* Ab = (t & 1) ? As[1] : As[0];
    __bf16* Bb = (t & 1) ? Bs[1] : Bs[0];
    __bf16* An = (t & 1) ? As[0] : As[1];
    __bf16* Bn = (t & 1) ? Bs[0] : Bs[1];
    const int k1 = (t + 1) * 64;
    const bool pf = (t < NT - 1);
    bf16x8 bv[4], av[2];

    // ---- p1: (mh0,kk0); stage Bh0'; retire Ah1(t) ----
    LOAD_BV128(Bb, sw0);
    LOAD_AV128(Ab, 0, sw0);
    if (pf) STAGE_B128(Bn, 0, k1);
    __builtin_amdgcn_s_barrier();
    WAITLGKM128();
    MFMA_P128(0);
    if (pf) asm volatile("s_waitcnt vmcnt(2)" ::: "memory");
    else    asm volatile("s_waitcnt vmcnt(0)" ::: "memory");
    __builtin_amdgcn_s_barrier();
    // ---- p2: (mh1,kk0); stage Bh1' ----
    LOAD_AV128(Ab, 1, sw0);
    if (pf) STAGE_B128(Bn, 1, k1);
    __builtin_amdgcn_s_barrier();
    WAITLGKM128();
    MFMA_P128(1);
    __builtin_amdgcn_s_barrier();
    // ---- p3: (mh0,kk1); stage Ah0' ----
    LOAD_BV128(Bb, sw1);
    LOAD_AV128(Ab, 0, sw1);
    if (pf) STAGE_A128(An, 0, k1);
    __builtin_amdgcn_s_barrier();
    WAITLGKM128();
    MFMA_P128(0);
    __builtin_amdgcn_s_barrier();
    // ---- p4: (mh1,kk1); stage Ah1'; retire B'+Ah0' ----
    LOAD_AV128(Ab, 1, sw1);
    if (pf) STAGE_A128(An, 1, k1);
    __builtin_amdgcn_s_barrier();
    WAITLGKM128();
    MFMA_P128(1);
    if (pf) asm volatile("s_waitcnt vmcnt(2)" ::: "memory");
    __builtin_amdgcn_s_barrier();
  }

  // epilogue. C/D layout: col = lane&15, row = (lane>>4)*4 + reg
#pragma unroll
  for (int mh = 0; mh < 2; ++mh) {
#pragma unroll
    for (int f = 0; f < 2; ++f) {
      const int row0 = m0 + wm * 64 + mh * 32 + f * 16 + kgrp * 4;
#pragma unroll
      for (int g = 0; g < 4; ++g) {
        const int col = n0 + wn * 64 + g * 16 + r16;
        const float bc = bias[col];
        const int head = col >> 6;
        f32x4 v = acc[mh * 2 + f][g];
#pragma unroll
        for (int r = 0; r < 4; ++r) {
          const int row = row0 + r;
          if constexpr (GATE) {
            float gg = gate[(size_t)row * NH + head];
            ((__bf16*)Cp)[(size_t)row * D_ + col] = (__bf16)((v[r] + bc) * gg);
          } else {
            ((float*)Cp)[(size_t)row * D_ + col] = v[r] + bc;
          }
        }
      }
    }
  }
#undef STAGE_B128
#undef STAGE_A128
#undef LOAD_BV128
#undef LOAD_AV128
#undef MFMA_P128
#undef WAITLGKM128
}

// ---------- 256x256 / BK=64 bf16 MFMA GEMM, 8-barrier m201-style phases ----------
// EXACT R12/R15/R16 structure (frozen: 168-172 µs).
template <bool GATE>
__global__ __launch_bounds__(512, 2) void gemm_nt(const __bf16* __restrict__ A,
                                                  const __bf16* __restrict__ Bt,
                                                  const float* __restrict__ bias,
                                                  const float* __restrict__ gate,
                                                  void* __restrict__ Cp) {
  __shared__ __bf16 As[2][256 * 64];
  __shared__ __bf16 Bs[2][256 * 64];
  const int tid = threadIdx.x;
  const int lane = tid & 63, wid = tid >> 6;
  const int wm = wid >> 2, wn = wid & 3;           // 2 x 4 waves
  const int r16 = lane & 15, kgrp = lane >> 4;
  const int bswz = (blockIdx.x & 7) * 128 + (blockIdx.x >> 3);
  const int m0 = (bswz >> 2) * 256;
  const int n0 = (bswz & 3) * 256;

  const int srow = lane >> 3;
  const int scol = ((lane & 7) ^ srow) * 8;        // pre-swizzled source col

  const int sw0 = ((kgrp) ^ (r16 & 7)) * 8;
  const int sw1 = ((4 + kgrp) ^ (r16 & 7)) * 8;

  f32x4 acc[8][4] = {};   // [mh*4+f][nh*2+g]

#define STAGE_HALF(dstbuf, srcp, base0, h, k0)                                  \
  {                                                                             \
    _Pragma("unroll") for (int j = 0; j < 2; ++j) {                             \
      const int c = (h) * 16 + wid * 2 + j;                                     \
      gload_lds16((srcp) + (size_t)((base0) + c * 8 + srow) * D_ + (k0) + scol, \
                  &(dstbuf)[c * 512]);                                          \
    }                                                                           \
  }

#define LOAD_BV(Bb, sw)                                                         \
  _Pragma("unroll") for (int nh = 0; nh < 2; ++nh)                              \
    _Pragma("unroll") for (int g = 0; g < 2; ++g)                               \
      bv[nh * 2 + g] = *reinterpret_cast<const bf16x8*>(                        \
          &(Bb)[(nh * 128 + wn * 32 + g * 16 + r16) * 64 + (sw)]);

#define LOAD_AV(Ab, mh, sw)                                                     \
  _Pragma("unroll") for (int f = 0; f < 4; ++f)                                 \
    av[f] = *reinterpret_cast<const bf16x8*>(                                   \
        &(Ab)[((mh) * 128 + wm * 64 + f * 16 + r16) * 64 + (sw)]);

#define MFMA_PHASE(mh)                                                          \
  {                                                                             \
    __builtin_amdgcn_s_setprio(1);                                              \
    _Pragma("unroll") for (int f = 0; f < 4; ++f)                               \
      _Pragma("unroll") for (int q = 0; q < 4; ++q)                             \
        acc[(mh) * 4 + f][q] = __builtin_amdgcn_mfma_f32_16x16x32_bf16(         \
            av[f], bv[q], acc[(mh) * 4 + f][q], 0, 0, 0);                       \
    __builtin_amdgcn_s_setprio(0);                                              \
  }

#define WAITLGKM()                                                              \
  asm volatile("s_waitcnt lgkmcnt(0)" ::: "memory");                            \
  __builtin_amdgcn_sched_barrier(0);

  // prologue: tile 0 = Bh0,Bh1,Ah0,Ah1; retire all but Ah1(0).
  STAGE_HALF(Bs[0], Bt, n0, 0, 0);
  STAGE_HALF(Bs[0], Bt, n0, 1, 0);
  STAGE_HALF(As[0], A,  m0, 0, 0);
  STAGE_HALF(As[0], A,  m0, 1, 0);
  asm volatile("s_waitcnt vmcnt(2)" ::: "memory");
  __builtin_amdgcn_s_barrier();

  const int NT = D_ / 64;   // 16
  for (int t = 0; t < NT; ++t) {
    __bf16* Ab = (t & 1) ? As[1] : As[0];
    __bf16* Bb = (t & 1) ? Bs[1] : Bs[0];
    __bf16* An = (t & 1) ? As[0] : As[1];
    __bf16* Bn = (t & 1) ? Bs[0] : Bs[1];
    const int k1 = (t + 1) * 64;
    const bool pf = (t < NT - 1);
    bf16x8 bv[4], av[4];

    // ---- p1: (mh0, kk0); stage Bh0(t+1); retire Ah1(t) ----
    LOAD_BV(Bb, sw0);
    LOAD_AV(Ab, 0, sw0);
    if (pf) STAGE_HALF(Bn, Bt, n0, 0, k1);
    __builtin_amdgcn_s_barrier();
    WAITLGKM();
    MFMA_PHASE(0);
    if (pf) asm volatile("s_waitcnt vmcnt(2)" ::: "memory");
    else    asm volatile("s_waitcnt vmcnt(0)" ::: "memory");
    __builtin_amdgcn_s_barrier();
    // ---- p2: (mh1, kk0); stage Bh1(t+1) ----
    LOAD_AV(Ab, 1, sw0);
    if (pf) STAGE_HALF(Bn, Bt, n0, 1, k1);
    __builtin_amdgcn_s_barrier();
    WAITLGKM();
    MFMA_PHASE(1);
    __builtin_amdgcn_s_barrier();
    // ---- p3: (mh0, kk1); stage Ah0(t+1) ----
    LOAD_BV(Bb, sw1);
    LOAD_AV(Ab, 0, sw1);
    if (pf) STAGE_HALF(An, A, m0, 0, k1);
    __builtin_amdgcn_s_barrier();
    WAITLGKM();
    MFMA_PHASE(0);
    __builtin_amdgcn_s_barrier();
    // ---- p4: (mh1, kk1); stage Ah1(t+1); retire B(t+1)+Ah0(t+1) ----
    LOAD_AV(Ab, 1, sw1);
    if (pf) STAGE_HALF(An, A, m0, 1, k1);
    __builtin_amdgcn_s_barrier();
    WAITLGKM();
    MFMA_PHASE(1);
    if (pf) asm volatile("s_waitcnt vmcnt(2)" ::: "memory");
    __builtin_amdgcn_s_barrier();
  }

  // epilogue. C/D layout: col = lane&15, row = (lane>>4)*4 + reg
#pragma unroll
  for (int mh = 0; mh < 2; ++mh) {
#pragma unroll
    for (int f = 0; f < 4; ++f) {
      const int row0 = m0 + mh * 128 + wm * 64 + f * 16 + kgrp * 4;
#pragma unroll
      for (int nh = 0; nh < 2; ++nh) {
#pragma unroll
        for (int g = 0; g < 2; ++g) {
          const int col = n0 + nh * 128 + wn * 32 + g * 16 + r16;
          const float bc = bias[col];
          const int head = col >> 6;
          f32x4 v = acc[mh * 4 + f][nh * 2 + g];
#pragma unroll
          for (int r = 0; r < 4; ++r) {
            const int row = row0 + r;
            if constexpr (GATE) {
              float gg = gate[(size_t)row * NH + head];
              ((__bf16*)Cp)[(size_t)row * D_ + col] = (__bf16)((v[r] + bc) * gg);
            } else {
              ((float*)Cp)[(size_t)row * D_ + col] = v[r] + bc;
            }
          }
        }
      }
    }
  }
#undef STAGE_HALF
#undef LOAD_BV
#undef LOAD_AV
#undef MFMA_PHASE
#undef WAITLGKM
}

extern "C" void kernel_launch(void* const* d_in, const int* in_sizes, int n_in,
                              void* d_out, int out_size, void* d_ws, size_t ws_size,
                              hipStream_t stream) {
  const float* hs  = (const float*)d_in[0];   // [16,1,1024]
  const float* kvs = (const float*)d_in[1];   // [16,4096,1024]
  const float* Wq  = (const float*)d_in[2];
  const float* bq  = (const float*)d_in[3];
  const float* Wk  = (const float*)d_in[4];
  const float* bk  = (const float*)d_in[5];
  const float* Wv  = (const float*)d_in[6];
  const float* bv  = (const float*)d_in[7];
  const float* Wo  = (const float*)d_in[8];
  const float* bo  = (const float*)d_in[9];
  float* out = (float*)d_out;

  char* w = (char*)d_ws;
  __bf16* ctx  = (__bf16*)w;  w += (size_t)NROWS * D_ * 2;    // 128 MB gated context (bf16)
  float*  attn = (float*)w;   w += (size_t)NROWS * NH * 4;    // 4 MB gate [row][head]
  __bf16* WvB  = (__bf16*)w;  w += (size_t)D_ * D_ * 2;       // 2 MB
  __bf16* WoB  = (__bf16*)w;  w += (size_t)D_ * D_ * 2;       // 2 MB
  __bf16* whi  = (__bf16*)w;  w += (size_t)B_ * NH * D_ * 2;  // 512 KB
  __bf16* wlo  = (__bf16*)w;  w += (size_t)B_ * NH * D_ * 2;  // 512 KB
  float*  cbuf = (float*)w;   w += B_ * NH * 4;               // 1 KB

  // bf16 copy of kvs lives in d_out (128 MB of its 256 MB); written by
  // scores_mfma (== bf16(kvs) exactly), consumed by GEMM1, then fully
  // overwritten by GEMM2's epilogue. No cross-call state.
  __bf16* kvsB = (__bf16*)d_out;

  conv_w_kernel<<<2048, 256, 0, stream>>>(Wv, Wo, WvB, WoB);
  wqeff_kernel<<<dim3(NH, B_), 256, 0, stream>>>(hs, Wq, bq, Wk, bk, whi, wlo, cbuf);
  scores_mfma_kernel<<<dim3(KL / 64, B_), 512, 0, stream>>>(kvs, whi, wlo, cbuf, attn, kvsB);
  gemm_128<true ><<<4096, 256, 0, stream>>>(kvsB, WvB, bv, attn, ctx);   // A/B: 128^2 TLP variant
  gemm_nt <false><<<1024, 512, 0, stream>>>(ctx, WoB, bo, (const float*)nullptr, (void*)out);
}

// Round 20
// 438.249 us; speedup vs baseline: 3.0362x; 1.0836x over previous
//
#include <hip/hip_runtime.h>
#include <hip/hip_bf16.h>
#include <stdint.h>

typedef __bf16 bf16x8 __attribute__((ext_vector_type(8)));
typedef __bf16 bf16x4 __attribute__((ext_vector_type(4)));
typedef float  f32x4  __attribute__((ext_vector_type(4)));

#define B_  16
#define KL  4096
#define D_  1024
#define NH  16
#define NROWS (B_*KL)   // 65536

__device__ __forceinline__ void gload_lds16(const void* g, void* l) {
  __builtin_amdgcn_global_load_lds(
      (__attribute__((address_space(1))) void*)g,
      (__attribute__((address_space(3))) void*)l, 16, 0, 0);
}

// ---------- small prep kernels ----------

__global__ __launch_bounds__(256) void conv_w_kernel(const float* __restrict__ wv,
                                                     const float* __restrict__ wo,
                                                     __bf16* __restrict__ dv,
                                                     __bf16* __restrict__ do_) {
  const bool second = blockIdx.x >= 1024;
  const int i = (second ? blockIdx.x - 1024 : blockIdx.x) * 256 + threadIdx.x;
  const float* s = second ? wo : wv;
  __bf16* d = second ? do_ : dv;
  float4 v = reinterpret_cast<const float4*>(s)[i];
  bf16x4 o;
  o[0] = (__bf16)v.x; o[1] = (__bf16)v.y; o[2] = (__bf16)v.z; o[3] = (__bf16)v.w;
  *reinterpret_cast<bf16x4*>(d + (size_t)i * 4) = o;
}

// Fused q-projection + wq_eff (verified R16 structure).
__global__ __launch_bounds__(256) void wqeff_kernel(const float* __restrict__ hs,
                                                    const float* __restrict__ Wq,
                                                    const float* __restrict__ bq,
                                                    const float* __restrict__ Wk,
                                                    const float* __restrict__ bk,
                                                    __bf16* __restrict__ whi,
                                                    __bf16* __restrict__ wlo,
                                                    float* __restrict__ cb) {
  const int h = blockIdx.x, b = blockIdx.y;
  const int tid = threadIdx.x;
  __shared__ float hsl[D_];
  __shared__ float ql[64];
  {
    float4 v = reinterpret_cast<const float4*>(hs + (size_t)b * D_)[tid];
    hsl[tid * 4] = v.x; hsl[tid * 4 + 1] = v.y;
    hsl[tid * 4 + 2] = v.z; hsl[tid * 4 + 3] = v.w;
  }
  __syncthreads();
  {
    const int d = tid >> 2, seg = tid & 3;
    const float* wr = Wq + (size_t)(h * 64 + d) * D_ + seg * 256;
    const float* xs = hsl + seg * 256;
    float p = 0.f;
    for (int i = 0; i < 256; i += 4) {
      float4 wv4 = *reinterpret_cast<const float4*>(wr + i);
      p += xs[i] * wv4.x + xs[i + 1] * wv4.y + xs[i + 2] * wv4.z + xs[i + 3] * wv4.w;
    }
    p += __shfl_xor(p, 1);
    p += __shfl_xor(p, 2);
    if (seg == 0) ql[d] = (p + bq[h * 64 + d]) * 0.125f;
  }
  __syncthreads();
  float a0 = 0, a1 = 0, a2 = 0, a3 = 0;
  for (int d = 0; d < 64; ++d) {
    float qv = ql[d];
    const float* wr = Wk + (size_t)(h * 64 + d) * D_;
    a0 += qv * wr[tid];
    a1 += qv * wr[tid + 256];
    a2 += qv * wr[tid + 512];
    a3 += qv * wr[tid + 768];
  }
  const size_t base = ((size_t)b * NH + h) * D_;
  float a[4] = {a0, a1, a2, a3};
#pragma unroll
  for (int j = 0; j < 4; ++j) {
    __bf16 hi = (__bf16)a[j];
    whi[base + j * 256 + tid] = hi;
    wlo[base + j * 256 + tid] = (__bf16)(a[j] - (float)hi);
  }
  if (tid < 64) {
    float p = ql[tid] * bk[h * 64 + tid];
    p += __shfl_down(p, 32); p += __shfl_down(p, 16); p += __shfl_down(p, 8);
    p += __shfl_down(p, 4);  p += __shfl_down(p, 2);  p += __shfl_down(p, 1);
    if (tid == 0) cb[b * NH + h] = p;
  }
}

// Scores via split-bf16 MFMA, K-SPLIT x2 (verified R16 structure).
__global__ __launch_bounds__(512) void scores_mfma_kernel(
    const float* __restrict__ kvs,   // [B, KL, D]
    const __bf16* __restrict__ whi,  // [B*NH, D]
    const __bf16* __restrict__ wlo,  // [B*NH, D]
    const float* __restrict__ cb,    // [B*NH]
    float* __restrict__ attn,        // [B*KL, NH]
    __bf16* __restrict__ kvd) {      // [B*KL, D]
  __shared__ f32x4 part[4][64];
  const int b = blockIdx.y;
  const int tid = threadIdx.x;
  const int lane = tid & 63, wv = tid >> 6;       // 8 waves
  const int rg = wv & 3;                          // row-group 0..3
  const int kh = wv >> 2;                         // K-half 0/1
  const int r16 = lane & 15, kgrp = lane >> 4;
  const int row0 = blockIdx.x * 64 + rg * 16;
  const size_t grow = (size_t)b * KL + row0;
  const int kbase = kh * 512;

  const float* xrow = kvs + (grow + r16) * D_ + kbase + kgrp * 8;
  __bf16*      krow = kvd + (grow + r16) * D_ + kbase + kgrp * 8;
  const __bf16* wh = whi + ((size_t)b * NH + r16) * D_ + kbase + kgrp * 8;
  const __bf16* wl = wlo + ((size_t)b * NH + r16) * D_ + kbase + kgrp * 8;

  f32x4 acc0 = {}, acc1 = {};

#define SPROC(xx0, xx1, kk)                                                     \
  {                                                                             \
    bf16x8 bh = *reinterpret_cast<const bf16x8*>(wh + (kk));                    \
    bf16x8 bl = *reinterpret_cast<const bf16x8*>(wl + (kk));                    \
    float xs[8] = {xx0.x, xx0.y, xx0.z, xx0.w, xx1.x, xx1.y, xx1.z, xx1.w};     \
    bf16x8 hi, lo;                                                              \
    _Pragma("unroll") for (int i = 0; i < 8; ++i) {                             \
      __bf16 h = (__bf16)xs[i];                                                 \
      hi[i] = h;                                                                \
      lo[i] = (__bf16)(xs[i] - (float)h);                                       \
    }                                                                           \
    *reinterpret_cast<bf16x8*>(krow + (kk)) = hi;                               \
    acc0 = __builtin_amdgcn_mfma_f32_16x16x32_bf16(hi, bh, acc0, 0, 0, 0);      \
    acc1 = __builtin_amdgcn_mfma_f32_16x16x32_bf16(hi, bl, acc1, 0, 0, 0);      \
    acc1 = __builtin_amdgcn_mfma_f32_16x16x32_bf16(lo, bh, acc1, 0, 0, 0);      \
  }

  float4 xa0 = *reinterpret_cast<const float4*>(xrow);
  float4 xa1 = *reinterpret_cast<const float4*>(xrow + 4);
  float4 xb0 = *reinterpret_cast<const float4*>(xrow + 32);
  float4 xb1 = *reinterpret_cast<const float4*>(xrow + 36);
  for (int k0 = 0; k0 < 512; k0 += 64) {
    float4 na0, na1, nb0, nb1;
    if (k0 + 64 < 512) {
      na0 = *reinterpret_cast<const float4*>(xrow + k0 + 64);
      na1 = *reinterpret_cast<const float4*>(xrow + k0 + 68);
      nb0 = *reinterpret_cast<const float4*>(xrow + k0 + 96);
      nb1 = *reinterpret_cast<const float4*>(xrow + k0 + 100);
    }
    SPROC(xa0, xa1, k0);
    SPROC(xb0, xb1, k0 + 32);
    xa0 = na0; xa1 = na1; xb0 = nb0; xb1 = nb1;
  }
#undef SPROC

  if (kh == 1) {
    f32x4 s = acc0;
#pragma unroll
    for (int r = 0; r < 4; ++r) s[r] += acc1[r];
    part[rg][lane] = s;
  }
  __syncthreads();
  if (kh == 0) {
    f32x4 p = part[rg][lane];
    const float c = cb[b * NH + r16];             // head = r16 in C layout
#pragma unroll
    for (int r = 0; r < 4; ++r) {
      const int orow = row0 + kgrp * 4 + r;
      float s = acc0[r] + acc1[r] + p[r] + c;
      attn[((size_t)b * KL + orow) * NH + r16] = fminf(fmaxf(s, 0.f), 1.f);
    }
  }
}

// ---------- 256x256 / BK=64 GEMM, QUADRANT phases + single vmcnt(6)/tile ----------
// m201-faithful variant (A/B on GEMM1). Phase = C-quadrant (mh,nh) over FULL
// K=64: p1=(0,0) reads av0[8]+bv0[4]; p2=(0,1) reads bv1[4] (av0 persists);
// p3=(1,0) reads av1[8] (bv0 persists); p4=(1,1) no ds_read (av1,bv1 persist).
// Each LDS half is ds_read in exactly ONE phase -> dies early -> staging can
// spread 1 half/phase with races excluded by the barrier pairs:
//   p1: (t+1).Ah1 -> next-buf      [region dead since (t-1).p3]
//   p2: (t+2).Ah0 -> CURRENT buf   [dead since p1]
//   p3: (t+2).Bh0 -> CURRENT buf   [dead since p1]
//   p4: (t+2).Bh1 -> CURRENT buf   [dead since p2]
// ONE wait per tile at p4-end: vmcnt(6) retires (t+1) fully, retire ages
// 3-6 phases (vs R12's two age-1 retires). Steady in-flight = 3 halves.
// Tail: t=NT-2 -> vmcnt(0); t=NT-1 compute-only. Accumulation order per acc
// element identical to R12 -> bit-identical C.
template <bool GATE>
__global__ __launch_bounds__(512, 2) void gemm_q(const __bf16* __restrict__ A,
                                                 const __bf16* __restrict__ Bt,
                                                 const float* __restrict__ bias,
                                                 const float* __restrict__ gate,
                                                 void* __restrict__ Cp) {
  __shared__ __bf16 As[2][256 * 64];
  __shared__ __bf16 Bs[2][256 * 64];
  const int tid = threadIdx.x;
  const int lane = tid & 63, wid = tid >> 6;
  const int wm = wid >> 2, wn = wid & 3;           // 2 x 4 waves
  const int r16 = lane & 15, kgrp = lane >> 4;
  const int bswz = (blockIdx.x & 7) * 128 + (blockIdx.x >> 3);
  const int m0 = (bswz >> 2) * 256;
  const int n0 = (bswz & 3) * 256;

  const int srow = lane >> 3;
  const int scol = ((lane & 7) ^ srow) * 8;        // pre-swizzled source col

  const int sw0 = ((kgrp) ^ (r16 & 7)) * 8;
  const int sw1 = ((4 + kgrp) ^ (r16 & 7)) * 8;

  f32x4 acc[8][4] = {};   // [mh*4+f][nh*2+g]

#define STAGE_HALF(dstbuf, srcp, base0, h, k0)                                  \
  {                                                                             \
    _Pragma("unroll") for (int j = 0; j < 2; ++j) {                             \
      const int c = (h) * 16 + wid * 2 + j;                                     \
      gload_lds16((srcp) + (size_t)((base0) + c * 8 + srow) * D_ + (k0) + scol, \
                  &(dstbuf)[c * 512]);                                          \
    }                                                                           \
  }

// av[kk*4+f] over both kk slices of A-half mh
#define LOAD_AVQ(Ab, mh)                                                        \
  _Pragma("unroll") for (int kk = 0; kk < 2; ++kk)                              \
    _Pragma("unroll") for (int f = 0; f < 4; ++f)                               \
      av[kk * 4 + f] = *reinterpret_cast<const bf16x8*>(                        \
          &(Ab)[((mh) * 128 + wm * 64 + f * 16 + r16) * 64 + (kk ? sw1 : sw0)]);

// dst[kk*2+g] over both kk slices of B-half nh
#define LOAD_BVQ(dst, Bb, nh)                                                   \
  _Pragma("unroll") for (int kk = 0; kk < 2; ++kk)                              \
    _Pragma("unroll") for (int g = 0; g < 2; ++g)                               \
      dst[kk * 2 + g] = *reinterpret_cast<const bf16x8*>(                       \
          &(Bb)[((nh) * 128 + wn * 32 + g * 16 + r16) * 64 + (kk ? sw1 : sw0)]);

#define MFMA_Q(mh, nh, bvx)                                                     \
  {                                                                             \
    __builtin_amdgcn_s_setprio(1);                                              \
    _Pragma("unroll") for (int kk = 0; kk < 2; ++kk)                            \
      _Pragma("unroll") for (int f = 0; f < 4; ++f)                             \
        _Pragma("unroll") for (int g = 0; g < 2; ++g)                           \
          acc[(mh) * 4 + f][(nh) * 2 + g] =                                     \
              __builtin_amdgcn_mfma_f32_16x16x32_bf16(                          \
                  av[kk * 4 + f], bvx[kk * 2 + g],                              \
                  acc[(mh) * 4 + f][(nh) * 2 + g], 0, 0, 0);                    \
    __builtin_amdgcn_s_setprio(0);                                              \
  }

#define WAITLGKMQ()                                                             \
  asm volatile("s_waitcnt lgkmcnt(0)" ::: "memory");                            \
  __builtin_amdgcn_sched_barrier(0);

  // prologue: 0.{Ah0,Bh0,Bh1,Ah1} + 1.{Ah0,Bh0,Bh1} (14 loads);
  // vmcnt(6) retires tile 0 fully, leaves 1's three halves in flight.
  STAGE_HALF(As[0], A,  m0, 0, 0);
  STAGE_HALF(Bs[0], Bt, n0, 0, 0);
  STAGE_HALF(Bs[0], Bt, n0, 1, 0);
  STAGE_HALF(As[0], A,  m0, 1, 0);
  STAGE_HALF(As[1], A,  m0, 0, 64);
  STAGE_HALF(Bs[1], Bt, n0, 0, 64);
  STAGE_HALF(Bs[1], Bt, n0, 1, 64);
  asm volatile("s_waitcnt vmcnt(6)" ::: "memory");
  __builtin_amdgcn_s_barrier();

  const int NT = D_ / 64;   // 16
  for (int t = 0; t < NT; ++t) {
    __bf16* Ab = (t & 1) ? As[1] : As[0];
    __bf16* Bb = (t & 1) ? Bs[1] : Bs[0];
    __bf16* An = (t & 1) ? As[0] : As[1];
    const int k1 = (t + 1) * 64;
    const int k2 = (t + 2) * 64;
    const bool pf1 = (t + 1 < NT);
    const bool pf2 = (t + 2 < NT);
    bf16x8 av[8], bv0[4], bv1[4];

    // ---- p1: quadrant (0,0); stage (t+1).Ah1 -> next buf ----
    LOAD_AVQ(Ab, 0);
    LOAD_BVQ(bv0, Bb, 0);
    if (pf1) STAGE_HALF(An, A, m0, 1, k1);
    __builtin_amdgcn_s_barrier();
    WAITLGKMQ();
    MFMA_Q(0, 0, bv0);
    __builtin_amdgcn_s_barrier();
    // ---- p2: quadrant (0,1); stage (t+2).Ah0 -> current buf ----
    LOAD_BVQ(bv1, Bb, 1);
    if (pf2) STAGE_HALF(Ab, A, m0, 0, k2);
    __builtin_amdgcn_s_barrier();
    WAITLGKMQ();
    MFMA_Q(0, 1, bv1);
    __builtin_amdgcn_s_barrier();
    // ---- p3: quadrant (1,0); stage (t+2).Bh0 -> current buf ----
    LOAD_AVQ(Ab, 1);
    if (pf2) STAGE_HALF(Bb, Bt, n0, 0, k2);
    __builtin_amdgcn_s_barrier();
    WAITLGKMQ();
    MFMA_Q(1, 0, bv0);
    __builtin_amdgcn_s_barrier();
    // ---- p4: quadrant (1,1); stage (t+2).Bh1 -> current buf; single wait ----
    if (pf2) STAGE_HALF(Bb, Bt, n0, 1, k2);
    __builtin_amdgcn_s_barrier();
    MFMA_Q(1, 1, bv1);
    if (pf2)      asm volatile("s_waitcnt vmcnt(6)" ::: "memory");
    else if (pf1) asm volatile("s_waitcnt vmcnt(0)" ::: "memory");
    __builtin_amdgcn_s_barrier();
  }

  // epilogue. C/D layout: col = lane&15, row = (lane>>4)*4 + reg
#pragma unroll
  for (int mh = 0; mh < 2; ++mh) {
#pragma unroll
    for (int f = 0; f < 4; ++f) {
      const int row0 = m0 + mh * 128 + wm * 64 + f * 16 + kgrp * 4;
#pragma unroll
      for (int nh = 0; nh < 2; ++nh) {
#pragma unroll
        for (int g = 0; g < 2; ++g) {
          const int col = n0 + nh * 128 + wn * 32 + g * 16 + r16;
          const float bc = bias[col];
          const int head = col >> 6;
          f32x4 v = acc[mh * 4 + f][nh * 2 + g];
#pragma unroll
          for (int r = 0; r < 4; ++r) {
            const int row = row0 + r;
            if constexpr (GATE) {
              float gg = gate[(size_t)row * NH + head];
              ((__bf16*)Cp)[(size_t)row * D_ + col] = (__bf16)((v[r] + bc) * gg);
            } else {
              ((float*)Cp)[(size_t)row * D_ + col] = v[r] + bc;
            }
          }
        }
      }
    }
  }
#undef STAGE_HALF
#undef LOAD_AVQ
#undef LOAD_BVQ
#undef MFMA_Q
#undef WAITLGKMQ
}

// ---------- 256x256 / BK=64 bf16 MFMA GEMM, 8-barrier m201-style phases ----------
// EXACT R12/R15/R16 structure (frozen: 168-172 µs).
template <bool GATE>
__global__ __launch_bounds__(512, 2) void gemm_nt(const __bf16* __restrict__ A,
                                                  const __bf16* __restrict__ Bt,
                                                  const float* __restrict__ bias,
                                                  const float* __restrict__ gate,
                                                  void* __restrict__ Cp) {
  __shared__ __bf16 As[2][256 * 64];
  __shared__ __bf16 Bs[2][256 * 64];
  const int tid = threadIdx.x;
  const int lane = tid & 63, wid = tid >> 6;
  const int wm = wid >> 2, wn = wid & 3;           // 2 x 4 waves
  const int r16 = lane & 15, kgrp = lane >> 4;
  const int bswz = (blockIdx.x & 7) * 128 + (blockIdx.x >> 3);
  const int m0 = (bswz >> 2) * 256;
  const int n0 = (bswz & 3) * 256;

  const int srow = lane >> 3;
  const int scol = ((lane & 7) ^ srow) * 8;        // pre-swizzled source col

  const int sw0 = ((kgrp) ^ (r16 & 7)) * 8;
  const int sw1 = ((4 + kgrp) ^ (r16 & 7)) * 8;

  f32x4 acc[8][4] = {};   // [mh*4+f][nh*2+g]

#define STAGE_HALF(dstbuf, srcp, base0, h, k0)                                  \
  {                                                                             \
    _Pragma("unroll") for (int j = 0; j < 2; ++j) {                             \
      const int c = (h) * 16 + wid * 2 + j;                                     \
      gload_lds16((srcp) + (size_t)((base0) + c * 8 + srow) * D_ + (k0) + scol, \
                  &(dstbuf)[c * 512]);                                          \
    }                                                                           \
  }

#define LOAD_BV(Bb, sw)                                                         \
  _Pragma("unroll") for (int nh = 0; nh < 2; ++nh)                              \
    _Pragma("unroll") for (int g = 0; g < 2; ++g)                               \
      bv[nh * 2 + g] = *reinterpret_cast<const bf16x8*>(                        \
          &(Bb)[(nh * 128 + wn * 32 + g * 16 + r16) * 64 + (sw)]);

#define LOAD_AV(Ab, mh, sw)                                                     \
  _Pragma("unroll") for (int f = 0; f < 4; ++f)                                 \
    av[f] = *reinterpret_cast<const bf16x8*>(                                   \
        &(Ab)[((mh) * 128 + wm * 64 + f * 16 + r16) * 64 + (sw)]);

#define MFMA_PHASE(mh)                                                          \
  {                                                                             \
    __builtin_amdgcn_s_setprio(1);                                              \
    _Pragma("unroll") for (int f = 0; f < 4; ++f)                               \
      _Pragma("unroll") for (int q = 0; q < 4; ++q)                             \
        acc[(mh) * 4 + f][q] = __builtin_amdgcn_mfma_f32_16x16x32_bf16(         \
            av[f], bv[q], acc[(mh) * 4 + f][q], 0, 0, 0);                       \
    __builtin_amdgcn_s_setprio(0);                                              \
  }

#define WAITLGKM()                                                              \
  asm volatile("s_waitcnt lgkmcnt(0)" ::: "memory");                            \
  __builtin_amdgcn_sched_barrier(0);

  // prologue: tile 0 = Bh0,Bh1,Ah0,Ah1; retire all but Ah1(0).
  STAGE_HALF(Bs[0], Bt, n0, 0, 0);
  STAGE_HALF(Bs[0], Bt, n0, 1, 0);
  STAGE_HALF(As[0], A,  m0, 0, 0);
  STAGE_HALF(As[0], A,  m0, 1, 0);
  asm volatile("s_waitcnt vmcnt(2)" ::: "memory");
  __builtin_amdgcn_s_barrier();

  const int NT = D_ / 64;   // 16
  for (int t = 0; t < NT; ++t) {
    __bf16* Ab = (t & 1) ? As[1] : As[0];
    __bf16* Bb = (t & 1) ? Bs[1] : Bs[0];
    __bf16* An = (t & 1) ? As[0] : As[1];
    __bf16* Bn = (t & 1) ? Bs[0] : Bs[1];
    const int k1 = (t + 1) * 64;
    const bool pf = (t < NT - 1);
    bf16x8 bv[4], av[4];

    // ---- p1: (mh0, kk0); stage Bh0(t+1); retire Ah1(t) ----
    LOAD_BV(Bb, sw0);
    LOAD_AV(Ab, 0, sw0);
    if (pf) STAGE_HALF(Bn, Bt, n0, 0, k1);
    __builtin_amdgcn_s_barrier();
    WAITLGKM();
    MFMA_PHASE(0);
    if (pf) asm volatile("s_waitcnt vmcnt(2)" ::: "memory");
    else    asm volatile("s_waitcnt vmcnt(0)" ::: "memory");
    __builtin_amdgcn_s_barrier();
    // ---- p2: (mh1, kk0); stage Bh1(t+1) ----
    LOAD_AV(Ab, 1, sw0);
    if (pf) STAGE_HALF(Bn, Bt, n0, 1, k1);
    __builtin_amdgcn_s_barrier();
    WAITLGKM();
    MFMA_PHASE(1);
    __builtin_amdgcn_s_barrier();
    // ---- p3: (mh0, kk1); stage Ah0(t+1) ----
    LOAD_BV(Bb, sw1);
    LOAD_AV(Ab, 0, sw1);
    if (pf) STAGE_HALF(An, A, m0, 0, k1);
    __builtin_amdgcn_s_barrier();
    WAITLGKM();
    MFMA_PHASE(0);
    __builtin_amdgcn_s_barrier();
    // ---- p4: (mh1, kk1); stage Ah1(t+1); retire B(t+1)+Ah0(t+1) ----
    LOAD_AV(Ab, 1, sw1);
    if (pf) STAGE_HALF(An, A, m0, 1, k1);
    __builtin_amdgcn_s_barrier();
    WAITLGKM();
    MFMA_PHASE(1);
    if (pf) asm volatile("s_waitcnt vmcnt(2)" ::: "memory");
    __builtin_amdgcn_s_barrier();
  }

  // epilogue. C/D layout: col = lane&15, row = (lane>>4)*4 + reg
#pragma unroll
  for (int mh = 0; mh < 2; ++mh) {
#pragma unroll
    for (int f = 0; f < 4; ++f) {
      const int row0 = m0 + mh * 128 + wm * 64 + f * 16 + kgrp * 4;
#pragma unroll
      for (int nh = 0; nh < 2; ++nh) {
#pragma unroll
        for (int g = 0; g < 2; ++g) {
          const int col = n0 + nh * 128 + wn * 32 + g * 16 + r16;
          const float bc = bias[col];
          const int head = col >> 6;
          f32x4 v = acc[mh * 4 + f][nh * 2 + g];
#pragma unroll
          for (int r = 0; r < 4; ++r) {
            const int row = row0 + r;
            if constexpr (GATE) {
              float gg = gate[(size_t)row * NH + head];
              ((__bf16*)Cp)[(size_t)row * D_ + col] = (__bf16)((v[r] + bc) * gg);
            } else {
              ((float*)Cp)[(size_t)row * D_ + col] = v[r] + bc;
            }
          }
        }
      }
    }
  }
#undef STAGE_HALF
#undef LOAD_BV
#undef LOAD_AV
#undef MFMA_PHASE
#undef WAITLGKM
}

extern "C" void kernel_launch(void* const* d_in, const int* in_sizes, int n_in,
                              void* d_out, int out_size, void* d_ws, size_t ws_size,
                              hipStream_t stream) {
  const float* hs  = (const float*)d_in[0];   // [16,1,1024]
  const float* kvs = (const float*)d_in[1];   // [16,4096,1024]
  const float* Wq  = (const float*)d_in[2];
  const float* bq  = (const float*)d_in[3];
  const float* Wk  = (const float*)d_in[4];
  const float* bk  = (const float*)d_in[5];
  const float* Wv  = (const float*)d_in[6];
  const float* bv  = (const float*)d_in[7];
  const float* Wo  = (const float*)d_in[8];
  const float* bo  = (const float*)d_in[9];
  float* out = (float*)d_out;

  char* w = (char*)d_ws;
  __bf16* ctx  = (__bf16*)w;  w += (size_t)NROWS * D_ * 2;    // 128 MB gated context (bf16)
  float*  attn = (float*)w;   w += (size_t)NROWS * NH * 4;    // 4 MB gate [row][head]
  __bf16* WvB  = (__bf16*)w;  w += (size_t)D_ * D_ * 2;       // 2 MB
  __bf16* WoB  = (__bf16*)w;  w += (size_t)D_ * D_ * 2;       // 2 MB
  __bf16* whi  = (__bf16*)w;  w += (size_t)B_ * NH * D_ * 2;  // 512 KB
  __bf16* wlo  = (__bf16*)w;  w += (size_t)B_ * NH * D_ * 2;  // 512 KB
  float*  cbuf = (float*)w;   w += B_ * NH * 4;               // 1 KB

  // bf16 copy of kvs lives in d_out (128 MB of its 256 MB); written by
  // scores_mfma (== bf16(kvs) exactly), consumed by GEMM1, then fully
  // overwritten by GEMM2's epilogue. No cross-call state.
  __bf16* kvsB = (__bf16*)d_out;

  conv_w_kernel<<<2048, 256, 0, stream>>>(Wv, Wo, WvB, WoB);
  wqeff_kernel<<<dim3(NH, B_), 256, 0, stream>>>(hs, Wq, bq, Wk, bk, whi, wlo, cbuf);
  scores_mfma_kernel<<<dim3(KL / 64, B_), 512, 0, stream>>>(kvs, whi, wlo, cbuf, attn, kvsB);
  gemm_q <true ><<<1024, 512, 0, stream>>>(kvsB, WvB, bv, attn, ctx);    // A/B: quadrant single-wait
  gemm_nt<false><<<1024, 512, 0, stream>>>(ctx, WoB, bo, (const float*)nullptr, (void*)out);
}

// Round 21
// 436.650 us; speedup vs baseline: 3.0473x; 1.0037x over previous
//
#include <hip/hip_runtime.h>
#include <hip/hip_bf16.h>
#include <stdint.h>

typedef __bf16 bf16x8 __attribute__((ext_vector_type(8)));
typedef __bf16 bf16x4 __attribute__((ext_vector_type(4)));
typedef float  f32x4  __attribute__((ext_vector_type(4)));

#define B_  16
#define KL  4096
#define D_  1024
#define NH  16
#define NROWS (B_*KL)   // 65536

__device__ __forceinline__ void gload_lds16(const void* g, void* l) {
  __builtin_amdgcn_global_load_lds(
      (__attribute__((address_space(1))) void*)g,
      (__attribute__((address_space(3))) void*)l, 16, 0, 0);
}

// ---------- small prep kernels ----------

__global__ __launch_bounds__(256) void conv_w_kernel(const float* __restrict__ wv,
                                                     const float* __restrict__ wo,
                                                     __bf16* __restrict__ dv,
                                                     __bf16* __restrict__ do_) {
  const bool second = blockIdx.x >= 1024;
  const int i = (second ? blockIdx.x - 1024 : blockIdx.x) * 256 + threadIdx.x;
  const float* s = second ? wo : wv;
  __bf16* d = second ? do_ : dv;
  float4 v = reinterpret_cast<const float4*>(s)[i];
  bf16x4 o;
  o[0] = (__bf16)v.x; o[1] = (__bf16)v.y; o[2] = (__bf16)v.z; o[3] = (__bf16)v.w;
  *reinterpret_cast<bf16x4*>(d + (size_t)i * 4) = o;
}

// Fused q-projection + wq_eff (verified R16 structure).
__global__ __launch_bounds__(256) void wqeff_kernel(const float* __restrict__ hs,
                                                    const float* __restrict__ Wq,
                                                    const float* __restrict__ bq,
                                                    const float* __restrict__ Wk,
                                                    const float* __restrict__ bk,
                                                    __bf16* __restrict__ whi,
                                                    __bf16* __restrict__ wlo,
                                                    float* __restrict__ cb) {
  const int h = blockIdx.x, b = blockIdx.y;
  const int tid = threadIdx.x;
  __shared__ float hsl[D_];
  __shared__ float ql[64];
  {
    float4 v = reinterpret_cast<const float4*>(hs + (size_t)b * D_)[tid];
    hsl[tid * 4] = v.x; hsl[tid * 4 + 1] = v.y;
    hsl[tid * 4 + 2] = v.z; hsl[tid * 4 + 3] = v.w;
  }
  __syncthreads();
  {
    const int d = tid >> 2, seg = tid & 3;
    const float* wr = Wq + (size_t)(h * 64 + d) * D_ + seg * 256;
    const float* xs = hsl + seg * 256;
    float p = 0.f;
    for (int i = 0; i < 256; i += 4) {
      float4 wv4 = *reinterpret_cast<const float4*>(wr + i);
      p += xs[i] * wv4.x + xs[i + 1] * wv4.y + xs[i + 2] * wv4.z + xs[i + 3] * wv4.w;
    }
    p += __shfl_xor(p, 1);
    p += __shfl_xor(p, 2);
    if (seg == 0) ql[d] = (p + bq[h * 64 + d]) * 0.125f;
  }
  __syncthreads();
  float a0 = 0, a1 = 0, a2 = 0, a3 = 0;
  for (int d = 0; d < 64; ++d) {
    float qv = ql[d];
    const float* wr = Wk + (size_t)(h * 64 + d) * D_;
    a0 += qv * wr[tid];
    a1 += qv * wr[tid + 256];
    a2 += qv * wr[tid + 512];
    a3 += qv * wr[tid + 768];
  }
  const size_t base = ((size_t)b * NH + h) * D_;
  float a[4] = {a0, a1, a2, a3};
#pragma unroll
  for (int j = 0; j < 4; ++j) {
    __bf16 hi = (__bf16)a[j];
    whi[base + j * 256 + tid] = hi;
    wlo[base + j * 256 + tid] = (__bf16)(a[j] - (float)hi);
  }
  if (tid < 64) {
    float p = ql[tid] * bk[h * 64 + tid];
    p += __shfl_down(p, 32); p += __shfl_down(p, 16); p += __shfl_down(p, 8);
    p += __shfl_down(p, 4);  p += __shfl_down(p, 2);  p += __shfl_down(p, 1);
    if (tid == 0) cb[b * NH + h] = p;
  }
}

// Scores via split-bf16 MFMA, K-SPLIT x2 (verified R16 structure).
__global__ __launch_bounds__(512) void scores_mfma_kernel(
    const float* __restrict__ kvs,   // [B, KL, D]
    const __bf16* __restrict__ whi,  // [B*NH, D]
    const __bf16* __restrict__ wlo,  // [B*NH, D]
    const float* __restrict__ cb,    // [B*NH]
    float* __restrict__ attn,        // [B*KL, NH]
    __bf16* __restrict__ kvd) {      // [B*KL, D]
  __shared__ f32x4 part[4][64];
  const int b = blockIdx.y;
  const int tid = threadIdx.x;
  const int lane = tid & 63, wv = tid >> 6;       // 8 waves
  const int rg = wv & 3;                          // row-group 0..3
  const int kh = wv >> 2;                         // K-half 0/1
  const int r16 = lane & 15, kgrp = lane >> 4;
  const int row0 = blockIdx.x * 64 + rg * 16;
  const size_t grow = (size_t)b * KL + row0;
  const int kbase = kh * 512;

  const float* xrow = kvs + (grow + r16) * D_ + kbase + kgrp * 8;
  __bf16*      krow = kvd + (grow + r16) * D_ + kbase + kgrp * 8;
  const __bf16* wh = whi + ((size_t)b * NH + r16) * D_ + kbase + kgrp * 8;
  const __bf16* wl = wlo + ((size_t)b * NH + r16) * D_ + kbase + kgrp * 8;

  f32x4 acc0 = {}, acc1 = {};

#define SPROC(xx0, xx1, kk)                                                     \
  {                                                                             \
    bf16x8 bh = *reinterpret_cast<const bf16x8*>(wh + (kk));                    \
    bf16x8 bl = *reinterpret_cast<const bf16x8*>(wl + (kk));                    \
    float xs[8] = {xx0.x, xx0.y, xx0.z, xx0.w, xx1.x, xx1.y, xx1.z, xx1.w};     \
    bf16x8 hi, lo;                                                              \
    _Pragma("unroll") for (int i = 0; i < 8; ++i) {                             \
      __bf16 h = (__bf16)xs[i];                                                 \
      hi[i] = h;                                                                \
      lo[i] = (__bf16)(xs[i] - (float)h);                                       \
    }                                                                           \
    *reinterpret_cast<bf16x8*>(krow + (kk)) = hi;                               \
    acc0 = __builtin_amdgcn_mfma_f32_16x16x32_bf16(hi, bh, acc0, 0, 0, 0);      \
    acc1 = __builtin_amdgcn_mfma_f32_16x16x32_bf16(hi, bl, acc1, 0, 0, 0);      \
    acc1 = __builtin_amdgcn_mfma_f32_16x16x32_bf16(lo, bh, acc1, 0, 0, 0);      \
  }

  float4 xa0 = *reinterpret_cast<const float4*>(xrow);
  float4 xa1 = *reinterpret_cast<const float4*>(xrow + 4);
  float4 xb0 = *reinterpret_cast<const float4*>(xrow + 32);
  float4 xb1 = *reinterpret_cast<const float4*>(xrow + 36);
  for (int k0 = 0; k0 < 512; k0 += 64) {
    float4 na0, na1, nb0, nb1;
    if (k0 + 64 < 512) {
      na0 = *reinterpret_cast<const float4*>(xrow + k0 + 64);
      na1 = *reinterpret_cast<const float4*>(xrow + k0 + 68);
      nb0 = *reinterpret_cast<const float4*>(xrow + k0 + 96);
      nb1 = *reinterpret_cast<const float4*>(xrow + k0 + 100);
    }
    SPROC(xa0, xa1, k0);
    SPROC(xb0, xb1, k0 + 32);
    xa0 = na0; xa1 = na1; xb0 = nb0; xb1 = nb1;
  }
#undef SPROC

  if (kh == 1) {
    f32x4 s = acc0;
#pragma unroll
    for (int r = 0; r < 4; ++r) s[r] += acc1[r];
    part[rg][lane] = s;
  }
  __syncthreads();
  if (kh == 0) {
    f32x4 p = part[rg][lane];
    const float c = cb[b * NH + r16];             // head = r16 in C layout
#pragma unroll
    for (int r = 0; r < 4; ++r) {
      const int orow = row0 + kgrp * 4 + r;
      float s = acc0[r] + acc1[r] + p[r] + c;
      attn[((size_t)b * KL + orow) * NH + r16] = fminf(fmaxf(s, 0.f), 1.f);
    }
  }
}

// ---------- 256x256 / BK=64 GEMM, quadrant phases, NO lgkm pin (A/B) ----------
// gemm_q (R20, =165-167 µs) with the per-phase `lgkmcnt(0)+sched_barrier(0)`
// REMOVED: ds_reads are ordinary loads, so the compiler emits fine-grained
// lgkmcnt(N) per dependent MFMA, overlapping early MFMAs with late ds_reads
// (m97 asm evidence; m141: order-pinning costs). Correctness: every ds_read
// is consumed by an MFMA before the phase's closing barrier -> all reads
// retired before any re-stage of that region (ledger unchanged); s_barrier
// intrinsics + "memory"-clobbered vmcnt asm prevent cross-barrier motion.
template <bool GATE>
__global__ __launch_bounds__(512, 2) void gemm_q(const __bf16* __restrict__ A,
                                                 const __bf16* __restrict__ Bt,
                                                 const float* __restrict__ bias,
                                                 const float* __restrict__ gate,
                                                 void* __restrict__ Cp) {
  __shared__ __bf16 As[2][256 * 64];
  __shared__ __bf16 Bs[2][256 * 64];
  const int tid = threadIdx.x;
  const int lane = tid & 63, wid = tid >> 6;
  const int wm = wid >> 2, wn = wid & 3;           // 2 x 4 waves
  const int r16 = lane & 15, kgrp = lane >> 4;
  const int bswz = (blockIdx.x & 7) * 128 + (blockIdx.x >> 3);
  const int m0 = (bswz >> 2) * 256;
  const int n0 = (bswz & 3) * 256;

  const int srow = lane >> 3;
  const int scol = ((lane & 7) ^ srow) * 8;        // pre-swizzled source col

  const int sw0 = ((kgrp) ^ (r16 & 7)) * 8;
  const int sw1 = ((4 + kgrp) ^ (r16 & 7)) * 8;

  f32x4 acc[8][4] = {};   // [mh*4+f][nh*2+g]

#define STAGE_HALF(dstbuf, srcp, base0, h, k0)                                  \
  {                                                                             \
    _Pragma("unroll") for (int j = 0; j < 2; ++j) {                             \
      const int c = (h) * 16 + wid * 2 + j;                                     \
      gload_lds16((srcp) + (size_t)((base0) + c * 8 + srow) * D_ + (k0) + scol, \
                  &(dstbuf)[c * 512]);                                          \
    }                                                                           \
  }

// av[kk*4+f] over both kk slices of A-half mh
#define LOAD_AVQ(Ab, mh)                                                        \
  _Pragma("unroll") for (int kk = 0; kk < 2; ++kk)                              \
    _Pragma("unroll") for (int f = 0; f < 4; ++f)                               \
      av[kk * 4 + f] = *reinterpret_cast<const bf16x8*>(                        \
          &(Ab)[((mh) * 128 + wm * 64 + f * 16 + r16) * 64 + (kk ? sw1 : sw0)]);

// dst[kk*2+g] over both kk slices of B-half nh
#define LOAD_BVQ(dst, Bb, nh)                                                   \
  _Pragma("unroll") for (int kk = 0; kk < 2; ++kk)                              \
    _Pragma("unroll") for (int g = 0; g < 2; ++g)                               \
      dst[kk * 2 + g] = *reinterpret_cast<const bf16x8*>(                       \
          &(Bb)[((nh) * 128 + wn * 32 + g * 16 + r16) * 64 + (kk ? sw1 : sw0)]);

#define MFMA_Q(mh, nh, bvx)                                                     \
  {                                                                             \
    __builtin_amdgcn_s_setprio(1);                                              \
    _Pragma("unroll") for (int kk = 0; kk < 2; ++kk)                            \
      _Pragma("unroll") for (int f = 0; f < 4; ++f)                             \
        _Pragma("unroll") for (int g = 0; g < 2; ++g)                           \
          acc[(mh) * 4 + f][(nh) * 2 + g] =                                     \
              __builtin_amdgcn_mfma_f32_16x16x32_bf16(                          \
                  av[kk * 4 + f], bvx[kk * 2 + g],                              \
                  acc[(mh) * 4 + f][(nh) * 2 + g], 0, 0, 0);                    \
    __builtin_amdgcn_s_setprio(0);                                              \
  }

  // prologue: 0.{Ah0,Bh0,Bh1,Ah1} + 1.{Ah0,Bh0,Bh1} (14 loads);
  // vmcnt(6) retires tile 0 fully, leaves 1's three halves in flight.
  STAGE_HALF(As[0], A,  m0, 0, 0);
  STAGE_HALF(Bs[0], Bt, n0, 0, 0);
  STAGE_HALF(Bs[0], Bt, n0, 1, 0);
  STAGE_HALF(As[0], A,  m0, 1, 0);
  STAGE_HALF(As[1], A,  m0, 0, 64);
  STAGE_HALF(Bs[1], Bt, n0, 0, 64);
  STAGE_HALF(Bs[1], Bt, n0, 1, 64);
  asm volatile("s_waitcnt vmcnt(6)" ::: "memory");
  __builtin_amdgcn_s_barrier();

  const int NT = D_ / 64;   // 16
  for (int t = 0; t < NT; ++t) {
    __bf16* Ab = (t & 1) ? As[1] : As[0];
    __bf16* Bb = (t & 1) ? Bs[1] : Bs[0];
    __bf16* An = (t & 1) ? As[0] : As[1];
    const int k1 = (t + 1) * 64;
    const int k2 = (t + 2) * 64;
    const bool pf1 = (t + 1 < NT);
    const bool pf2 = (t + 2 < NT);
    bf16x8 av[8], bv0[4], bv1[4];

    // ---- p1: quadrant (0,0); stage (t+1).Ah1 -> next buf ----
    LOAD_AVQ(Ab, 0);
    LOAD_BVQ(bv0, Bb, 0);
    if (pf1) STAGE_HALF(An, A, m0, 1, k1);
    __builtin_amdgcn_s_barrier();
    MFMA_Q(0, 0, bv0);
    __builtin_amdgcn_s_barrier();
    // ---- p2: quadrant (0,1); stage (t+2).Ah0 -> current buf ----
    LOAD_BVQ(bv1, Bb, 1);
    if (pf2) STAGE_HALF(Ab, A, m0, 0, k2);
    __builtin_amdgcn_s_barrier();
    MFMA_Q(0, 1, bv1);
    __builtin_amdgcn_s_barrier();
    // ---- p3: quadrant (1,0); stage (t+2).Bh0 -> current buf ----
    LOAD_AVQ(Ab, 1);
    if (pf2) STAGE_HALF(Bb, Bt, n0, 0, k2);
    __builtin_amdgcn_s_barrier();
    MFMA_Q(1, 0, bv0);
    __builtin_amdgcn_s_barrier();
    // ---- p4: quadrant (1,1); stage (t+2).Bh1 -> current buf; single wait ----
    if (pf2) STAGE_HALF(Bb, Bt, n0, 1, k2);
    __builtin_amdgcn_s_barrier();
    MFMA_Q(1, 1, bv1);
    if (pf2)      asm volatile("s_waitcnt vmcnt(6)" ::: "memory");
    else if (pf1) asm volatile("s_waitcnt vmcnt(0)" ::: "memory");
    __builtin_amdgcn_s_barrier();
  }

  // epilogue. C/D layout: col = lane&15, row = (lane>>4)*4 + reg
#pragma unroll
  for (int mh = 0; mh < 2; ++mh) {
#pragma unroll
    for (int f = 0; f < 4; ++f) {
      const int row0 = m0 + mh * 128 + wm * 64 + f * 16 + kgrp * 4;
#pragma unroll
      for (int nh = 0; nh < 2; ++nh) {
#pragma unroll
        for (int g = 0; g < 2; ++g) {
          const int col = n0 + nh * 128 + wn * 32 + g * 16 + r16;
          const float bc = bias[col];
          const int head = col >> 6;
          f32x4 v = acc[mh * 4 + f][nh * 2 + g];
#pragma unroll
          for (int r = 0; r < 4; ++r) {
            const int row = row0 + r;
            if constexpr (GATE) {
              float gg = gate[(size_t)row * NH + head];
              ((__bf16*)Cp)[(size_t)row * D_ + col] = (__bf16)((v[r] + bc) * gg);
            } else {
              ((float*)Cp)[(size_t)row * D_ + col] = v[r] + bc;
            }
          }
        }
      }
    }
  }
#undef STAGE_HALF
#undef LOAD_AVQ
#undef LOAD_BVQ
#undef MFMA_Q
}

// ---------- 256x256 / BK=64 bf16 MFMA GEMM, 8-barrier m201-style phases ----------
// EXACT R12/R15/R16 structure (frozen control: 165-172 µs).
template <bool GATE>
__global__ __launch_bounds__(512, 2) void gemm_nt(const __bf16* __restrict__ A,
                                                  const __bf16* __restrict__ Bt,
                                                  const float* __restrict__ bias,
                                                  const float* __restrict__ gate,
                                                  void* __restrict__ Cp) {
  __shared__ __bf16 As[2][256 * 64];
  __shared__ __bf16 Bs[2][256 * 64];
  const int tid = threadIdx.x;
  const int lane = tid & 63, wid = tid >> 6;
  const int wm = wid >> 2, wn = wid & 3;           // 2 x 4 waves
  const int r16 = lane & 15, kgrp = lane >> 4;
  const int bswz = (blockIdx.x & 7) * 128 + (blockIdx.x >> 3);
  const int m0 = (bswz >> 2) * 256;
  const int n0 = (bswz & 3) * 256;

  const int srow = lane >> 3;
  const int scol = ((lane & 7) ^ srow) * 8;        // pre-swizzled source col

  const int sw0 = ((kgrp) ^ (r16 & 7)) * 8;
  const int sw1 = ((4 + kgrp) ^ (r16 & 7)) * 8;

  f32x4 acc[8][4] = {};   // [mh*4+f][nh*2+g]

#define STAGE_HALF(dstbuf, srcp, base0, h, k0)                                  \
  {                                                                             \
    _Pragma("unroll") for (int j = 0; j < 2; ++j) {                             \
      const int c = (h) * 16 + wid * 2 + j;                                     \
      gload_lds16((srcp) + (size_t)((base0) + c * 8 + srow) * D_ + (k0) + scol, \
                  &(dstbuf)[c * 512]);                                          \
    }                                                                           \
  }

#define LOAD_BV(Bb, sw)                                                         \
  _Pragma("unroll") for (int nh = 0; nh < 2; ++nh)                              \
    _Pragma("unroll") for (int g = 0; g < 2; ++g)                               \
      bv[nh * 2 + g] = *reinterpret_cast<const bf16x8*>(                        \
          &(Bb)[(nh * 128 + wn * 32 + g * 16 + r16) * 64 + (sw)]);

#define LOAD_AV(Ab, mh, sw)                                                     \
  _Pragma("unroll") for (int f = 0; f < 4; ++f)                                 \
    av[f] = *reinterpret_cast<const bf16x8*>(                                   \
        &(Ab)[((mh) * 128 + wm * 64 + f * 16 + r16) * 64 + (sw)]);

#define MFMA_PHASE(mh)                                                          \
  {                                                                             \
    __builtin_amdgcn_s_setprio(1);                                              \
    _Pragma("unroll") for (int f = 0; f < 4; ++f)                               \
      _Pragma("unroll") for (int q = 0; q < 4; ++q)                             \
        acc[(mh) * 4 + f][q] = __builtin_amdgcn_mfma_f32_16x16x32_bf16(         \
            av[f], bv[q], acc[(mh) * 4 + f][q], 0, 0, 0);                       \
    __builtin_amdgcn_s_setprio(0);                                              \
  }

#define WAITLGKM()                                                              \
  asm volatile("s_waitcnt lgkmcnt(0)" ::: "memory");                            \
  __builtin_amdgcn_sched_barrier(0);

  // prologue: tile 0 = Bh0,Bh1,Ah0,Ah1; retire all but Ah1(0).
  STAGE_HALF(Bs[0], Bt, n0, 0, 0);
  STAGE_HALF(Bs[0], Bt, n0, 1, 0);
  STAGE_HALF(As[0], A,  m0, 0, 0);
  STAGE_HALF(As[0], A,  m0, 1, 0);
  asm volatile("s_waitcnt vmcnt(2)" ::: "memory");
  __builtin_amdgcn_s_barrier();

  const int NT = D_ / 64;   // 16
  for (int t = 0; t < NT; ++t) {
    __bf16* Ab = (t & 1) ? As[1] : As[0];
    __bf16* Bb = (t & 1) ? Bs[1] : Bs[0];
    __bf16* An = (t & 1) ? As[0] : As[1];
    __bf16* Bn = (t & 1) ? Bs[0] : Bs[1];
    const int k1 = (t + 1) * 64;
    const bool pf = (t < NT - 1);
    bf16x8 bv[4], av[4];

    // ---- p1: (mh0, kk0); stage Bh0(t+1); retire Ah1(t) ----
    LOAD_BV(Bb, sw0);
    LOAD_AV(Ab, 0, sw0);
    if (pf) STAGE_HALF(Bn, Bt, n0, 0, k1);
    __builtin_amdgcn_s_barrier();
    WAITLGKM();
    MFMA_PHASE(0);
    if (pf) asm volatile("s_waitcnt vmcnt(2)" ::: "memory");
    else    asm volatile("s_waitcnt vmcnt(0)" ::: "memory");
    __builtin_amdgcn_s_barrier();
    // ---- p2: (mh1, kk0); stage Bh1(t+1) ----
    LOAD_AV(Ab, 1, sw0);
    if (pf) STAGE_HALF(Bn, Bt, n0, 1, k1);
    __builtin_amdgcn_s_barrier();
    WAITLGKM();
    MFMA_PHASE(1);
    __builtin_amdgcn_s_barrier();
    // ---- p3: (mh0, kk1); stage Ah0(t+1) ----
    LOAD_BV(Bb, sw1);
    LOAD_AV(Ab, 0, sw1);
    if (pf) STAGE_HALF(An, A, m0, 0, k1);
    __builtin_amdgcn_s_barrier();
    WAITLGKM();
    MFMA_PHASE(0);
    __builtin_amdgcn_s_barrier();
    // ---- p4: (mh1, kk1); stage Ah1(t+1); retire B(t+1)+Ah0(t+1) ----
    LOAD_AV(Ab, 1, sw1);
    if (pf) STAGE_HALF(An, A, m0, 1, k1);
    __builtin_amdgcn_s_barrier();
    WAITLGKM();
    MFMA_PHASE(1);
    if (pf) asm volatile("s_waitcnt vmcnt(2)" ::: "memory");
    __builtin_amdgcn_s_barrier();
  }

  // epilogue. C/D layout: col = lane&15, row = (lane>>4)*4 + reg
#pragma unroll
  for (int mh = 0; mh < 2; ++mh) {
#pragma unroll
    for (int f = 0; f < 4; ++f) {
      const int row0 = m0 + mh * 128 + wm * 64 + f * 16 + kgrp * 4;
#pragma unroll
      for (int nh = 0; nh < 2; ++nh) {
#pragma unroll
        for (int g = 0; g < 2; ++g) {
          const int col = n0 + nh * 128 + wn * 32 + g * 16 + r16;
          const float bc = bias[col];
          const int head = col >> 6;
          f32x4 v = acc[mh * 4 + f][nh * 2 + g];
#pragma unroll
          for (int r = 0; r < 4; ++r) {
            const int row = row0 + r;
            if constexpr (GATE) {
              float gg = gate[(size_t)row * NH + head];
              ((__bf16*)Cp)[(size_t)row * D_ + col] = (__bf16)((v[r] + bc) * gg);
            } else {
              ((float*)Cp)[(size_t)row * D_ + col] = v[r] + bc;
            }
          }
        }
      }
    }
  }
#undef STAGE_HALF
#undef LOAD_BV
#undef LOAD_AV
#undef MFMA_PHASE
#undef WAITLGKM
}

extern "C" void kernel_launch(void* const* d_in, const int* in_sizes, int n_in,
                              void* d_out, int out_size, void* d_ws, size_t ws_size,
                              hipStream_t stream) {
  const float* hs  = (const float*)d_in[0];   // [16,1,1024]
  const float* kvs = (const float*)d_in[1];   // [16,4096,1024]
  const float* Wq  = (const float*)d_in[2];
  const float* bq  = (const float*)d_in[3];
  const float* Wk  = (const float*)d_in[4];
  const float* bk  = (const float*)d_in[5];
  const float* Wv  = (const float*)d_in[6];
  const float* bv  = (const float*)d_in[7];
  const float* Wo  = (const float*)d_in[8];
  const float* bo  = (const float*)d_in[9];
  float* out = (float*)d_out;

  char* w = (char*)d_ws;
  __bf16* ctx  = (__bf16*)w;  w += (size_t)NROWS * D_ * 2;    // 128 MB gated context (bf16)
  float*  attn = (float*)w;   w += (size_t)NROWS * NH * 4;    // 4 MB gate [row][head]
  __bf16* WvB  = (__bf16*)w;  w += (size_t)D_ * D_ * 2;       // 2 MB
  __bf16* WoB  = (__bf16*)w;  w += (size_t)D_ * D_ * 2;       // 2 MB
  __bf16* whi  = (__bf16*)w;  w += (size_t)B_ * NH * D_ * 2;  // 512 KB
  __bf16* wlo  = (__bf16*)w;  w += (size_t)B_ * NH * D_ * 2;  // 512 KB
  float*  cbuf = (float*)w;   w += B_ * NH * 4;               // 1 KB

  // bf16 copy of kvs lives in d_out (128 MB of its 256 MB); written by
  // scores_mfma (== bf16(kvs) exactly), consumed by GEMM1, then fully
  // overwritten by GEMM2's epilogue. No cross-call state.
  __bf16* kvsB = (__bf16*)d_out;

  conv_w_kernel<<<2048, 256, 0, stream>>>(Wv, Wo, WvB, WoB);
  wqeff_kernel<<<dim3(NH, B_), 256, 0, stream>>>(hs, Wq, bq, Wk, bk, whi, wlo, cbuf);
  scores_mfma_kernel<<<dim3(KL / 64, B_), 512, 0, stream>>>(kvs, whi, wlo, cbuf, attn, kvsB);
  gemm_q <true ><<<1024, 512, 0, stream>>>(kvsB, WvB, bv, attn, ctx);    // A/B: no lgkm pin
  gemm_nt<false><<<1024, 512, 0, stream>>>(ctx, WoB, bo, (const float*)nullptr, (void*)out);
}

// Round 22
// 434.798 us; speedup vs baseline: 3.0603x; 1.0043x over previous
//
#include <hip/hip_runtime.h>
#include <hip/hip_bf16.h>
#include <stdint.h>

typedef __bf16 bf16x8 __attribute__((ext_vector_type(8)));
typedef __bf16 bf16x4 __attribute__((ext_vector_type(4)));
typedef float  f32x4  __attribute__((ext_vector_type(4)));

#define B_  16
#define KL  4096
#define D_  1024
#define NH  16
#define NROWS (B_*KL)   // 65536

__device__ __forceinline__ void gload_lds16(const void* g, void* l) {
  __builtin_amdgcn_global_load_lds(
      (__attribute__((address_space(1))) void*)g,
      (__attribute__((address_space(3))) void*)l, 16, 0, 0);
}

// ---------- small prep kernels ----------

__global__ __launch_bounds__(256) void conv_w_kernel(const float* __restrict__ wv,
                                                     const float* __restrict__ wo,
                                                     __bf16* __restrict__ dv,
                                                     __bf16* __restrict__ do_) {
  const bool second = blockIdx.x >= 1024;
  const int i = (second ? blockIdx.x - 1024 : blockIdx.x) * 256 + threadIdx.x;
  const float* s = second ? wo : wv;
  __bf16* d = second ? do_ : dv;
  float4 v = reinterpret_cast<const float4*>(s)[i];
  bf16x4 o;
  o[0] = (__bf16)v.x; o[1] = (__bf16)v.y; o[2] = (__bf16)v.z; o[3] = (__bf16)v.w;
  *reinterpret_cast<bf16x4*>(d + (size_t)i * 4) = o;
}

// Fused q-projection + wq_eff (verified R16 structure).
__global__ __launch_bounds__(256) void wqeff_kernel(const float* __restrict__ hs,
                                                    const float* __restrict__ Wq,
                                                    const float* __restrict__ bq,
                                                    const float* __restrict__ Wk,
                                                    const float* __restrict__ bk,
                                                    __bf16* __restrict__ whi,
                                                    __bf16* __restrict__ wlo,
                                                    float* __restrict__ cb) {
  const int h = blockIdx.x, b = blockIdx.y;
  const int tid = threadIdx.x;
  __shared__ float hsl[D_];
  __shared__ float ql[64];
  {
    float4 v = reinterpret_cast<const float4*>(hs + (size_t)b * D_)[tid];
    hsl[tid * 4] = v.x; hsl[tid * 4 + 1] = v.y;
    hsl[tid * 4 + 2] = v.z; hsl[tid * 4 + 3] = v.w;
  }
  __syncthreads();
  {
    const int d = tid >> 2, seg = tid & 3;
    const float* wr = Wq + (size_t)(h * 64 + d) * D_ + seg * 256;
    const float* xs = hsl + seg * 256;
    float p = 0.f;
    for (int i = 0; i < 256; i += 4) {
      float4 wv4 = *reinterpret_cast<const float4*>(wr + i);
      p += xs[i] * wv4.x + xs[i + 1] * wv4.y + xs[i + 2] * wv4.z + xs[i + 3] * wv4.w;
    }
    p += __shfl_xor(p, 1);
    p += __shfl_xor(p, 2);
    if (seg == 0) ql[d] = (p + bq[h * 64 + d]) * 0.125f;
  }
  __syncthreads();
  float a0 = 0, a1 = 0, a2 = 0, a3 = 0;
  for (int d = 0; d < 64; ++d) {
    float qv = ql[d];
    const float* wr = Wk + (size_t)(h * 64 + d) * D_;
    a0 += qv * wr[tid];
    a1 += qv * wr[tid + 256];
    a2 += qv * wr[tid + 512];
    a3 += qv * wr[tid + 768];
  }
  const size_t base = ((size_t)b * NH + h) * D_;
  float a[4] = {a0, a1, a2, a3};
#pragma unroll
  for (int j = 0; j < 4; ++j) {
    __bf16 hi = (__bf16)a[j];
    whi[base + j * 256 + tid] = hi;
    wlo[base + j * 256 + tid] = (__bf16)(a[j] - (float)hi);
  }
  if (tid < 64) {
    float p = ql[tid] * bk[h * 64 + tid];
    p += __shfl_down(p, 32); p += __shfl_down(p, 16); p += __shfl_down(p, 8);
    p += __shfl_down(p, 4);  p += __shfl_down(p, 2);  p += __shfl_down(p, 1);
    if (tid == 0) cb[b * NH + h] = p;
  }
}

// Scores via split-bf16 MFMA, K-SPLIT x2 (verified R16 structure).
__global__ __launch_bounds__(512) void scores_mfma_kernel(
    const float* __restrict__ kvs,   // [B, KL, D]
    const __bf16* __restrict__ whi,  // [B*NH, D]
    const __bf16* __restrict__ wlo,  // [B*NH, D]
    const float* __restrict__ cb,    // [B*NH]
    float* __restrict__ attn,        // [B*KL, NH]
    __bf16* __restrict__ kvd) {      // [B*KL, D]
  __shared__ f32x4 part[4][64];
  const int b = blockIdx.y;
  const int tid = threadIdx.x;
  const int lane = tid & 63, wv = tid >> 6;       // 8 waves
  const int rg = wv & 3;                          // row-group 0..3
  const int kh = wv >> 2;                         // K-half 0/1
  const int r16 = lane & 15, kgrp = lane >> 4;
  const int row0 = blockIdx.x * 64 + rg * 16;
  const size_t grow = (size_t)b * KL + row0;
  const int kbase = kh * 512;

  const float* xrow = kvs + (grow + r16) * D_ + kbase + kgrp * 8;
  __bf16*      krow = kvd + (grow + r16) * D_ + kbase + kgrp * 8;
  const __bf16* wh = whi + ((size_t)b * NH + r16) * D_ + kbase + kgrp * 8;
  const __bf16* wl = wlo + ((size_t)b * NH + r16) * D_ + kbase + kgrp * 8;

  f32x4 acc0 = {}, acc1 = {};

#define SPROC(xx0, xx1, kk)                                                     \
  {                                                                             \
    bf16x8 bh = *reinterpret_cast<const bf16x8*>(wh + (kk));                    \
    bf16x8 bl = *reinterpret_cast<const bf16x8*>(wl + (kk));                    \
    float xs[8] = {xx0.x, xx0.y, xx0.z, xx0.w, xx1.x, xx1.y, xx1.z, xx1.w};     \
    bf16x8 hi, lo;                                                              \
    _Pragma("unroll") for (int i = 0; i < 8; ++i) {                             \
      __bf16 h = (__bf16)xs[i];                                                 \
      hi[i] = h;                                                                \
      lo[i] = (__bf16)(xs[i] - (float)h);                                       \
    }                                                                           \
    *reinterpret_cast<bf16x8*>(krow + (kk)) = hi;                               \
    acc0 = __builtin_amdgcn_mfma_f32_16x16x32_bf16(hi, bh, acc0, 0, 0, 0);      \
    acc1 = __builtin_amdgcn_mfma_f32_16x16x32_bf16(hi, bl, acc1, 0, 0, 0);      \
    acc1 = __builtin_amdgcn_mfma_f32_16x16x32_bf16(lo, bh, acc1, 0, 0, 0);      \
  }

  float4 xa0 = *reinterpret_cast<const float4*>(xrow);
  float4 xa1 = *reinterpret_cast<const float4*>(xrow + 4);
  float4 xb0 = *reinterpret_cast<const float4*>(xrow + 32);
  float4 xb1 = *reinterpret_cast<const float4*>(xrow + 36);
  for (int k0 = 0; k0 < 512; k0 += 64) {
    float4 na0, na1, nb0, nb1;
    if (k0 + 64 < 512) {
      na0 = *reinterpret_cast<const float4*>(xrow + k0 + 64);
      na1 = *reinterpret_cast<const float4*>(xrow + k0 + 68);
      nb0 = *reinterpret_cast<const float4*>(xrow + k0 + 96);
      nb1 = *reinterpret_cast<const float4*>(xrow + k0 + 100);
    }
    SPROC(xa0, xa1, k0);
    SPROC(xb0, xb1, k0 + 32);
    xa0 = na0; xa1 = na1; xb0 = nb0; xb1 = nb1;
  }
#undef SPROC

  if (kh == 1) {
    f32x4 s = acc0;
#pragma unroll
    for (int r = 0; r < 4; ++r) s[r] += acc1[r];
    part[rg][lane] = s;
  }
  __syncthreads();
  if (kh == 0) {
    f32x4 p = part[rg][lane];
    const float c = cb[b * NH + r16];             // head = r16 in C layout
#pragma unroll
    for (int r = 0; r < 4; ++r) {
      const int orow = row0 + kgrp * 4 + r;
      float s = acc0[r] + acc1[r] + p[r] + c;
      attn[((size_t)b * KL + orow) * NH + r16] = fminf(fmaxf(s, 0.f), 1.f);
    }
  }
}

// ---------- 256x256 / BK=64 GEMM, quadrant phases, no lgkm pin ----------
// Final converged GEMM (R20 gemm_q + R21 pin removal; best measured).
// Phase = C-quadrant (mh,nh) over full K=64; staging 1 half/phase with
// single aged vmcnt(6)/tile; compiler fine-schedules ds_read->MFMA.
template <bool GATE>
__global__ __launch_bounds__(512, 2) void gemm_q(const __bf16* __restrict__ A,
                                                 const __bf16* __restrict__ Bt,
                                                 const float* __restrict__ bias,
                                                 const float* __restrict__ gate,
                                                 void* __restrict__ Cp) {
  __shared__ __bf16 As[2][256 * 64];
  __shared__ __bf16 Bs[2][256 * 64];
  const int tid = threadIdx.x;
  const int lane = tid & 63, wid = tid >> 6;
  const int wm = wid >> 2, wn = wid & 3;           // 2 x 4 waves
  const int r16 = lane & 15, kgrp = lane >> 4;
  const int bswz = (blockIdx.x & 7) * 128 + (blockIdx.x >> 3);
  const int m0 = (bswz >> 2) * 256;
  const int n0 = (bswz & 3) * 256;

  const int srow = lane >> 3;
  const int scol = ((lane & 7) ^ srow) * 8;        // pre-swizzled source col

  const int sw0 = ((kgrp) ^ (r16 & 7)) * 8;
  const int sw1 = ((4 + kgrp) ^ (r16 & 7)) * 8;

  f32x4 acc[8][4] = {};   // [mh*4+f][nh*2+g]

#define STAGE_HALF(dstbuf, srcp, base0, h, k0)                                  \
  {                                                                             \
    _Pragma("unroll") for (int j = 0; j < 2; ++j) {                             \
      const int c = (h) * 16 + wid * 2 + j;                                     \
      gload_lds16((srcp) + (size_t)((base0) + c * 8 + srow) * D_ + (k0) + scol, \
                  &(dstbuf)[c * 512]);                                          \
    }                                                                           \
  }

// av[kk*4+f] over both kk slices of A-half mh
#define LOAD_AVQ(Ab, mh)                                                        \
  _Pragma("unroll") for (int kk = 0; kk < 2; ++kk)                              \
    _Pragma("unroll") for (int f = 0; f < 4; ++f)                               \
      av[kk * 4 + f] = *reinterpret_cast<const bf16x8*>(                        \
          &(Ab)[((mh) * 128 + wm * 64 + f * 16 + r16) * 64 + (kk ? sw1 : sw0)]);

// dst[kk*2+g] over both kk slices of B-half nh
#define LOAD_BVQ(dst, Bb, nh)                                                   \
  _Pragma("unroll") for (int kk = 0; kk < 2; ++kk)                              \
    _Pragma("unroll") for (int g = 0; g < 2; ++g)                               \
      dst[kk * 2 + g] = *reinterpret_cast<const bf16x8*>(                       \
          &(Bb)[((nh) * 128 + wn * 32 + g * 16 + r16) * 64 + (kk ? sw1 : sw0)]);

#define MFMA_Q(mh, nh, bvx)                                                     \
  {                                                                             \
    __builtin_amdgcn_s_setprio(1);                                              \
    _Pragma("unroll") for (int kk = 0; kk < 2; ++kk)                            \
      _Pragma("unroll") for (int f = 0; f < 4; ++f)                             \
        _Pragma("unroll") for (int g = 0; g < 2; ++g)                           \
          acc[(mh) * 4 + f][(nh) * 2 + g] =                                     \
              __builtin_amdgcn_mfma_f32_16x16x32_bf16(                          \
                  av[kk * 4 + f], bvx[kk * 2 + g],                              \
                  acc[(mh) * 4 + f][(nh) * 2 + g], 0, 0, 0);                    \
    __builtin_amdgcn_s_setprio(0);                                              \
  }

  // prologue: 0.{Ah0,Bh0,Bh1,Ah1} + 1.{Ah0,Bh0,Bh1} (14 loads);
  // vmcnt(6) retires tile 0 fully, leaves 1's three halves in flight.
  STAGE_HALF(As[0], A,  m0, 0, 0);
  STAGE_HALF(Bs[0], Bt, n0, 0, 0);
  STAGE_HALF(Bs[0], Bt, n0, 1, 0);
  STAGE_HALF(As[0], A,  m0, 1, 0);
  STAGE_HALF(As[1], A,  m0, 0, 64);
  STAGE_HALF(Bs[1], Bt, n0, 0, 64);
  STAGE_HALF(Bs[1], Bt, n0, 1, 64);
  asm volatile("s_waitcnt vmcnt(6)" ::: "memory");
  __builtin_amdgcn_s_barrier();

  const int NT = D_ / 64;   // 16
  for (int t = 0; t < NT; ++t) {
    __bf16* Ab = (t & 1) ? As[1] : As[0];
    __bf16* Bb = (t & 1) ? Bs[1] : Bs[0];
    __bf16* An = (t & 1) ? As[0] : As[1];
    const int k1 = (t + 1) * 64;
    const int k2 = (t + 2) * 64;
    const bool pf1 = (t + 1 < NT);
    const bool pf2 = (t + 2 < NT);
    bf16x8 av[8], bv0[4], bv1[4];

    // ---- p1: quadrant (0,0); stage (t+1).Ah1 -> next buf ----
    LOAD_AVQ(Ab, 0);
    LOAD_BVQ(bv0, Bb, 0);
    if (pf1) STAGE_HALF(An, A, m0, 1, k1);
    __builtin_amdgcn_s_barrier();
    MFMA_Q(0, 0, bv0);
    __builtin_amdgcn_s_barrier();
    // ---- p2: quadrant (0,1); stage (t+2).Ah0 -> current buf ----
    LOAD_BVQ(bv1, Bb, 1);
    if (pf2) STAGE_HALF(Ab, A, m0, 0, k2);
    __builtin_amdgcn_s_barrier();
    MFMA_Q(0, 1, bv1);
    __builtin_amdgcn_s_barrier();
    // ---- p3: quadrant (1,0); stage (t+2).Bh0 -> current buf ----
    LOAD_AVQ(Ab, 1);
    if (pf2) STAGE_HALF(Bb, Bt, n0, 0, k2);
    __builtin_amdgcn_s_barrier();
    MFMA_Q(1, 0, bv0);
    __builtin_amdgcn_s_barrier();
    // ---- p4: quadrant (1,1); stage (t+2).Bh1 -> current buf; single wait ----
    if (pf2) STAGE_HALF(Bb, Bt, n0, 1, k2);
    __builtin_amdgcn_s_barrier();
    MFMA_Q(1, 1, bv1);
    if (pf2)      asm volatile("s_waitcnt vmcnt(6)" ::: "memory");
    else if (pf1) asm volatile("s_waitcnt vmcnt(0)" ::: "memory");
    __builtin_amdgcn_s_barrier();
  }

  // epilogue. C/D layout: col = lane&15, row = (lane>>4)*4 + reg
#pragma unroll
  for (int mh = 0; mh < 2; ++mh) {
#pragma unroll
    for (int f = 0; f < 4; ++f) {
      const int row0 = m0 + mh * 128 + wm * 64 + f * 16 + kgrp * 4;
#pragma unroll
      for (int nh = 0; nh < 2; ++nh) {
#pragma unroll
        for (int g = 0; g < 2; ++g) {
          const int col = n0 + nh * 128 + wn * 32 + g * 16 + r16;
          const float bc = bias[col];
          const int head = col >> 6;
          f32x4 v = acc[mh * 4 + f][nh * 2 + g];
#pragma unroll
          for (int r = 0; r < 4; ++r) {
            const int row = row0 + r;
            if constexpr (GATE) {
              float gg = gate[(size_t)row * NH + head];
              ((__bf16*)Cp)[(size_t)row * D_ + col] = (__bf16)((v[r] + bc) * gg);
            } else {
              ((float*)Cp)[(size_t)row * D_ + col] = v[r] + bc;
            }
          }
        }
      }
    }
  }
#undef STAGE_HALF
#undef LOAD_AVQ
#undef LOAD_BVQ
#undef MFMA_Q
}

extern "C" void kernel_launch(void* const* d_in, const int* in_sizes, int n_in,
                              void* d_out, int out_size, void* d_ws, size_t ws_size,
                              hipStream_t stream) {
  const float* hs  = (const float*)d_in[0];   // [16,1,1024]
  const float* kvs = (const float*)d_in[1];   // [16,4096,1024]
  const float* Wq  = (const float*)d_in[2];
  const float* bq  = (const float*)d_in[3];
  const float* Wk  = (const float*)d_in[4];
  const float* bk  = (const float*)d_in[5];
  const float* Wv  = (const float*)d_in[6];
  const float* bv  = (const float*)d_in[7];
  const float* Wo  = (const float*)d_in[8];
  const float* bo  = (const float*)d_in[9];
  float* out = (float*)d_out;

  char* w = (char*)d_ws;
  __bf16* ctx  = (__bf16*)w;  w += (size_t)NROWS * D_ * 2;    // 128 MB gated context (bf16)
  float*  attn = (float*)w;   w += (size_t)NROWS * NH * 4;    // 4 MB gate [row][head]
  __bf16* WvB  = (__bf16*)w;  w += (size_t)D_ * D_ * 2;       // 2 MB
  __bf16* WoB  = (__bf16*)w;  w += (size_t)D_ * D_ * 2;       // 2 MB
  __bf16* whi  = (__bf16*)w;  w += (size_t)B_ * NH * D_ * 2;  // 512 KB
  __bf16* wlo  = (__bf16*)w;  w += (size_t)B_ * NH * D_ * 2;  // 512 KB
  float*  cbuf = (float*)w;   w += B_ * NH * 4;               // 1 KB

  // bf16 copy of kvs lives in d_out (128 MB of its 256 MB); written by
  // scores_mfma (== bf16(kvs) exactly), consumed by GEMM1, then fully
  // overwritten by GEMM2's epilogue. No cross-call state.
  __bf16* kvsB = (__bf16*)d_out;

  conv_w_kernel<<<2048, 256, 0, stream>>>(Wv, Wo, WvB, WoB);
  wqeff_kernel<<<dim3(NH, B_), 256, 0, stream>>>(hs, Wq, bq, Wk, bk, whi, wlo, cbuf);
  scores_mfma_kernel<<<dim3(KL / 64, B_), 512, 0, stream>>>(kvs, whi, wlo, cbuf, attn, kvsB);
  gemm_q<true ><<<1024, 512, 0, stream>>>(kvsB, WvB, bv, attn, ctx);
  gemm_q<false><<<1024, 512, 0, stream>>>(ctx, WoB, bo, (const float*)nullptr, (void*)out);
}